// Round 11
// baseline (524.822 us; speedup 1.0000x reference)
//
#include <hip/hip_runtime.h>
#include <hip/hip_bf16.h>

// Problem constants (from reference)
#define NNODES 10000
#define NEDGES 320000
#define INF_   1280
#define HID_   128
#define HEADS_ 4
#define OUTF_  500
#define HC_    512          // HEADS_*HID_
#define NEG_SLOPE 0.2f
#define BN_EPS 1e-5f

typedef __attribute__((ext_vector_type(8))) short short8x;
typedef __attribute__((ext_vector_type(4))) float f32x4;
typedef unsigned short ushort_t;
typedef unsigned int uint_t;

__device__ __forceinline__ ushort_t f2bf(float f) {
    uint_t u = __float_as_uint(f);
    u = (u + 0x7fffu + ((u >> 16) & 1u)) >> 16;   // round-to-nearest-even
    return (ushort_t)u;
}
__device__ __forceinline__ float bf_lo(uint_t p) { return __uint_as_float(p << 16); }
__device__ __forceinline__ float bf_hi(uint_t p) { return __uint_as_float(p & 0xffff0000u); }
__device__ __forceinline__ float lrelu(float x) { return (x >= 0.f) ? x : NEG_SLOPE * x; }
__device__ __forceinline__ uint_t pack_bf16_rn(float a, float b) {
    __hip_bfloat162 h = __float22bfloat162_rn(make_float2(a, b));  // hw packed cvt, RNE
    return *(uint_t*)&h;
}

// ---------------------------------------------------------------------------
// utility
// ---------------------------------------------------------------------------
__global__ void zero_kernel(float* __restrict__ p, size_t n) {
    size_t i = (size_t)blockIdx.x * blockDim.x + threadIdx.x;
    size_t stride = (size_t)gridDim.x * blockDim.x;
    for (; i < n; i += stride) p[i] = 0.0f;
}

// one kernel: x->bf16 (VECTORIZED: float4 in, packed-cvt uint2 out) + weights
#define CVX (NNODES * INF_ / 4)        // 3,200,000 float4 chunks of x
#define CN1 (HC_ * INF_)               // Wt1: 512 rows x 1280
#define CN2 (HC_ * HC_)                // Wt2
#define CN3 (HC_ * HC_)                // Wt3 (padded rows)
__global__ void convall_kernel(const float* __restrict__ x,
                               const float* __restrict__ W1,
                               const float* __restrict__ W2,
                               const float* __restrict__ W3,
                               ushort_t* __restrict__ x_bf,
                               ushort_t* __restrict__ Wt1,
                               ushort_t* __restrict__ Wt2,
                               ushort_t* __restrict__ Wt3) {
    int i = blockIdx.x * blockDim.x + threadIdx.x;
    if (i < CVX) {
        float4 v = ((const float4*)x)[i];
        ((uint2*)x_bf)[i] = make_uint2(pack_bf16_rn(v.x, v.y), pack_bf16_rn(v.z, v.w));
    } else if (i < CVX + CN1) {
        int j = i - CVX;
        int n = j / INF_, k = j - n * INF_;
        Wt1[j] = f2bf(W1[(size_t)k * HC_ + n]);
    } else if (i < CVX + CN1 + CN2) {
        int j = i - CVX - CN1;
        int n = j / HC_, k = j - n * HC_;
        Wt2[j] = f2bf(W2[(size_t)k * HC_ + n]);
    } else if (i < CVX + CN1 + CN2 + CN3) {
        int j = i - CVX - CN1 - CN2;
        int n = j / HC_, k = j - n * HC_;
        Wt3[j] = (n < OUTF_) ? f2bf(W3[(size_t)k * OUTF_ + n]) : (ushort_t)0;
    }
}

// ---------------------------------------------------------------------------
// CSR build (by destination)
// ---------------------------------------------------------------------------
__global__ void count_kernel(const int* __restrict__ dst, int* __restrict__ counts, int E) {
    int e = blockIdx.x * blockDim.x + threadIdx.x;
    if (e < E) atomicAdd(&counts[dst[e]], 1);
}

__global__ __launch_bounds__(256) void scan1_kernel(const int* __restrict__ counts,
                                                    int* __restrict__ offsets,
                                                    int* __restrict__ bsum, int n) {
    __shared__ int tmp[256];
    int b = blockIdx.x, t = threadIdx.x;
    int i = b * 256 + t;
    int v = (i < n) ? counts[i] : 0;
    tmp[t] = v;
    __syncthreads();
    for (int off = 1; off < 256; off <<= 1) {
        int u = (t >= off) ? tmp[t - off] : 0;
        __syncthreads();
        tmp[t] += u;
        __syncthreads();
    }
    if (i < n) offsets[i] = tmp[t] - v;
    if (t == 255) bsum[b] = tmp[t];
}

__global__ __launch_bounds__(256) void scan3b_kernel(int* __restrict__ offsets,
                                                     int* __restrict__ cursor,
                                                     const int* __restrict__ bsum,
                                                     int nb, int n) {
    __shared__ int base_sh, tot_sh;
    int b = blockIdx.x, t = threadIdx.x;
    if (t == 0) {
        int acc = 0, tot = 0;
        for (int k = 0; k < nb; ++k) { if (k < b) acc += bsum[k]; tot += bsum[k]; }
        base_sh = acc; tot_sh = tot;
    }
    __syncthreads();
    int i = b * 256 + t;
    if (i < n) {
        int v = offsets[i] + base_sh;
        offsets[i] = v;
        cursor[i] = v;
    }
    if (b == nb - 1 && t == 0) offsets[n] = tot_sh;
}

__global__ void scatter_kernel(const int* __restrict__ src, const int* __restrict__ dst,
                               int* __restrict__ cursor, int* __restrict__ esrc, int E) {
    int e = blockIdx.x * blockDim.x + threadIdx.x;
    if (e < E) {
        int p = atomicAdd(&cursor[dst[e]], 1);
        esrc[p] = src[e];
    }
}

// ---------------------------------------------------------------------------
// bf16 MFMA GEMM with fused attention-logit epilogue.
//   R11 REVERT to empirically fastest config (R4): 64x64 tile, BK=32,
//   plain 2-D grid (NO XCD swizzle — swizzled variants were consistently
//   ~6-8 us slower despite 6x less HBM traffic; dispatch-imbalance theory),
//   bf16 A only (fp32-in-staging cost ~ linear in staged bytes, R8 vs R9).
//   256 thr = 4 waves in 2x2; wave = 32x32 quadrant (2x2 MFMAs).
// ---------------------------------------------------------------------------
#define LDT 40   // LDS row stride in bf16 units (padded)

__global__ __launch_bounds__(256) void gemm_fused_kernel(
    const ushort_t* __restrict__ A,    // [M][K] bf16
    const ushort_t* __restrict__ Bt,   // [512][K] bf16 (transposed, padded)
    ushort_t* __restrict__ Cb,         // [M][512] bf16
    const float* __restrict__ avS,     // a_src flat [N]
    const float* __restrict__ avD,     // a_dst flat [N]
    float* __restrict__ s_log,         // [M][H] (pre-zeroed)
    float* __restrict__ d_log,         // [M][H]
    int M, int K, int N, int H)
{
    __shared__ __align__(16) ushort_t As[64 * LDT];
    __shared__ __align__(16) ushort_t Bs[64 * LDT];

    int m0 = blockIdx.y * 64;
    int n0 = blockIdx.x * 64;

    int tid  = threadIdx.x;
    int lane = tid & 63;
    int w    = tid >> 6;
    int wm   = (w & 1) * 32;
    int wn   = (w >> 1) * 32;
    int quad = lane >> 4;
    int c16  = lane & 15;

    f32x4 acc[2][2];
#pragma unroll
    for (int i = 0; i < 2; ++i)
#pragma unroll
        for (int j = 0; j < 2; ++j)
#pragma unroll
            for (int r = 0; r < 4; ++r) acc[i][j][r] = 0.0f;

    int sr = tid >> 2;          // 0..63 row within tile
    int sk = (tid & 3) * 8;     // k chunk: 0,8,16,24

    for (int k0 = 0; k0 < K; k0 += 32) {
        int gm = m0 + sr;
        if (gm > M - 1) gm = M - 1;   // clamp tail rows (stores masked)
        uint4 av = *(const uint4*)(A + (size_t)gm * K + k0 + sk);
        *(uint4*)&As[sr * LDT + sk] = av;

        uint4 bv = *(const uint4*)(Bt + (size_t)(n0 + sr) * K + k0 + sk);
        *(uint4*)&Bs[sr * LDT + sk] = bv;
        __syncthreads();

        short8x af0 = *(const short8x*)&As[(wm +      c16) * LDT + quad * 8];
        short8x af1 = *(const short8x*)&As[(wm + 16 + c16) * LDT + quad * 8];
        short8x bf0 = *(const short8x*)&Bs[(wn +      c16) * LDT + quad * 8];
        short8x bf1 = *(const short8x*)&Bs[(wn + 16 + c16) * LDT + quad * 8];

        acc[0][0] = __builtin_amdgcn_mfma_f32_16x16x32_bf16(af0, bf0, acc[0][0], 0, 0, 0);
        acc[0][1] = __builtin_amdgcn_mfma_f32_16x16x32_bf16(af0, bf1, acc[0][1], 0, 0, 0);
        acc[1][0] = __builtin_amdgcn_mfma_f32_16x16x32_bf16(af1, bf0, acc[1][0], 0, 0, 0);
        acc[1][1] = __builtin_amdgcn_mfma_f32_16x16x32_bf16(af1, bf1, acc[1][1], 0, 0, 0);
        __syncthreads();
    }

    // ---- epilogue: C store + logit partials ----
    int col0 = n0 + wn + c16;
    int col1 = col0 + 16;
    float as0 = (col0 < N) ? avS[col0] : 0.f;
    float as1 = (col1 < N) ? avS[col1] : 0.f;
    float ad0 = (col0 < N) ? avD[col0] : 0.f;
    float ad1 = (col1 < N) ? avD[col1] : 0.f;

    float sv[8], dv[8];   // [mt*4+r]
#pragma unroll
    for (int mt = 0; mt < 2; ++mt) {
#pragma unroll
        for (int r = 0; r < 4; ++r) {
            float v0 = acc[mt][0][r];
            float v1 = acc[mt][1][r];
            sv[mt * 4 + r] = v0 * as0 + v1 * as1;
            dv[mt * 4 + r] = v0 * ad0 + v1 * ad1;
            int row = m0 + wm + mt * 16 + quad * 4 + r;
            if (row < M) {
                Cb[(size_t)row * 512 + col0] = f2bf(v0);
                Cb[(size_t)row * 512 + col1] = f2bf(v1);
            }
        }
    }
#pragma unroll
    for (int off = 1; off < 16; off <<= 1) {
#pragma unroll
        for (int i = 0; i < 8; ++i) {
            sv[i] += __shfl_xor(sv[i], off);
            dv[i] += __shfl_xor(dv[i], off);
        }
    }
    if (c16 == 0) {
        int hb = (H == 4) ? (n0 >> 7) : 0;
#pragma unroll
        for (int mt = 0; mt < 2; ++mt) {
#pragma unroll
            for (int r = 0; r < 4; ++r) {
                int row = m0 + wm + mt * 16 + quad * 4 + r;
                if (row < M) {
                    atomicAdd(&s_log[row * H + hb], sv[mt * 4 + r]);
                    atomicAdd(&d_log[row * H + hb], dv[mt * 4 + r]);
                }
            }
        }
    }
}

// ---------------------------------------------------------------------------
// FUSED edge softmax + weighted gather-aggregate (wave-per-node, 8-deep MLP).
// ---------------------------------------------------------------------------
__device__ __forceinline__ void acc8(float* acc, uint4 q, float w) {
    acc[0] += w * bf_lo(q.x); acc[1] += w * bf_hi(q.x);
    acc[2] += w * bf_lo(q.y); acc[3] += w * bf_hi(q.y);
    acc[4] += w * bf_lo(q.z); acc[5] += w * bf_hi(q.z);
    acc[6] += w * bf_lo(q.w); acc[7] += w * bf_hi(q.w);
}

template<int H>
__global__ __launch_bounds__(256) void softagg_kernel(
    const uint4* __restrict__ xpb4,     // [node][64] (512 bf16 / row)
    const float* __restrict__ s,        // [node][H]
    const float* __restrict__ dlog,     // [node][H]
    const int* __restrict__ offsets, const int* __restrict__ esrc,
    float* __restrict__ ew,             // [E][H] scratch
    const float* __restrict__ bias,     // [OUTC]
    float* __restrict__ out,            // [node][ldo]
    int OUTC, int ldo)
{
    int node = blockIdx.x * 4 + (threadIdx.x >> 6);
    if (node >= NNODES) return;
    int lane = threadIdx.x & 63;
    int e0 = offsets[node], e1 = offsets[node + 1];

    // ---- softmax phase ----
    float dh[H], selfe[H], mh[H], zh[H];
#pragma unroll
    for (int h = 0; h < H; ++h) {
        dh[h] = dlog[node * H + h];
        selfe[h] = lrelu(s[node * H + h] + dh[h]);
        mh[h] = selfe[h];
        zh[h] = 0.f;
    }
    for (int j = e0 + lane; j < e1; j += 64) {
        int src = esrc[j];
        if (H == 4) {
            float4 sv = ((const float4*)s)[src];
            mh[0] = fmaxf(mh[0], lrelu(sv.x + dh[0]));
            mh[1] = fmaxf(mh[1], lrelu(sv.y + dh[1]));
            mh[2] = fmaxf(mh[2], lrelu(sv.z + dh[2]));
            mh[3] = fmaxf(mh[3], lrelu(sv.w + dh[3]));
        } else {
#pragma unroll
            for (int h = 0; h < H; ++h)
                mh[h] = fmaxf(mh[h], lrelu(s[src * H + h] + dh[h]));
        }
    }
#pragma unroll
    for (int h = 0; h < H; ++h)
        for (int off = 32; off > 0; off >>= 1)
            mh[h] = fmaxf(mh[h], __shfl_xor(mh[h], off));

    for (int j = e0 + lane; j < e1; j += 64) {
        int src = esrc[j];
        if (H == 4) {
            float4 sv = ((const float4*)s)[src];
            float w0 = __expf(lrelu(sv.x + dh[0]) - mh[0]);
            float w1 = __expf(lrelu(sv.y + dh[1]) - mh[1]);
            float w2 = __expf(lrelu(sv.z + dh[2]) - mh[2]);
            float w3 = __expf(lrelu(sv.w + dh[3]) - mh[3]);
            ((float4*)ew)[j] = make_float4(w0, w1, w2, w3);
            zh[0] += w0; zh[1] += w1; zh[2] += w2; zh[3] += w3;
        } else {
#pragma unroll
            for (int h = 0; h < H; ++h) {
                float w = __expf(lrelu(s[src * H + h] + dh[h]) - mh[h]);
                ew[(size_t)j * H + h] = w;
                zh[h] += w;
            }
        }
    }
#pragma unroll
    for (int h = 0; h < H; ++h)
        for (int off = 32; off > 0; off >>= 1)
            zh[h] += __shfl_xor(zh[h], off);

    float ws_[H], zi_[H];
#pragma unroll
    for (int h = 0; h < H; ++h) {
        ws_[h] = __expf(selfe[h] - mh[h]);
        zi_[h] = 1.0f / (zh[h] + ws_[h]);
    }
    int hg = (H == 4) ? (lane >> 4) : 0;
    float ws, zi;
    if (H == 4) {
        ws = (hg == 0) ? ws_[0] : (hg == 1) ? ws_[1] : (hg == 2) ? ws_[2] : ws_[3];
        zi = (hg == 0) ? zi_[0] : (hg == 1) ? zi_[1] : (hg == 2) ? zi_[2] : zi_[3];
    } else { ws = ws_[0]; zi = zi_[0]; }

    // ---- gather phase (8-deep) ----
    uint4 p = xpb4[(size_t)node * 64 + lane];
    float acc[8];
    acc[0] = ws * bf_lo(p.x); acc[1] = ws * bf_hi(p.x);
    acc[2] = ws * bf_lo(p.y); acc[3] = ws * bf_hi(p.y);
    acc[4] = ws * bf_lo(p.z); acc[5] = ws * bf_hi(p.z);
    acc[6] = ws * bf_lo(p.w); acc[7] = ws * bf_hi(p.w);

    int j = e0;
    for (; j + 7 < e1; j += 8) {
        int ss[8]; float ww[8]; uint4 qq[8];
#pragma unroll
        for (int t = 0; t < 8; ++t) ss[t] = esrc[j + t];
#pragma unroll
        for (int t = 0; t < 8; ++t) ww[t] = ew[(size_t)(j + t) * H + hg];
#pragma unroll
        for (int t = 0; t < 8; ++t) qq[t] = xpb4[(size_t)ss[t] * 64 + lane];
#pragma unroll
        for (int t = 0; t < 8; ++t) acc8(acc, qq[t], ww[t]);
    }
    for (; j + 3 < e1; j += 4) {
        int s0 = esrc[j], s1 = esrc[j + 1], s2 = esrc[j + 2], s3 = esrc[j + 3];
        float w0 = ew[(size_t)j * H + hg];
        float w1 = ew[(size_t)(j + 1) * H + hg];
        float w2 = ew[(size_t)(j + 2) * H + hg];
        float w3 = ew[(size_t)(j + 3) * H + hg];
        uint4 q0 = xpb4[(size_t)s0 * 64 + lane];
        uint4 q1 = xpb4[(size_t)s1 * 64 + lane];
        uint4 q2 = xpb4[(size_t)s2 * 64 + lane];
        uint4 q3 = xpb4[(size_t)s3 * 64 + lane];
        acc8(acc, q0, w0);
        acc8(acc, q1, w1);
        acc8(acc, q2, w2);
        acc8(acc, q3, w3);
    }
    for (; j < e1; ++j) {
        int s0 = esrc[j];
        float w0 = ew[(size_t)j * H + hg];
        uint4 q0 = xpb4[(size_t)s0 * 64 + lane];
        acc8(acc, q0, w0);
    }

    int cbase = lane * 8;
    size_t ob = (size_t)node * ldo + cbase;
    if (cbase + 7 < OUTC) {
        float4 o0 = make_float4(acc[0] * zi + bias[cbase + 0], acc[1] * zi + bias[cbase + 1],
                                acc[2] * zi + bias[cbase + 2], acc[3] * zi + bias[cbase + 3]);
        float4 o1 = make_float4(acc[4] * zi + bias[cbase + 4], acc[5] * zi + bias[cbase + 5],
                                acc[6] * zi + bias[cbase + 6], acc[7] * zi + bias[cbase + 7]);
        *(float4*)(out + ob) = o0;
        *(float4*)(out + ob + 4) = o1;
    } else {
#pragma unroll
        for (int k = 0; k < 8; ++k) {
            int c = cbase + k;
            if (c < OUTC) out[ob + k] = acc[k] * zi + bias[c];
        }
    }
}

// ---------------------------------------------------------------------------
// BatchNorm: stats (64-block partials, folds next-layer logit zeroing) ->
// tiny finalize (scale/shift) -> wide apply+ELU+pack.
// ---------------------------------------------------------------------------
__global__ __launch_bounds__(512) void bn_stats_kernel(const float* __restrict__ h,
                                                       float* __restrict__ psum,
                                                       float* __restrict__ psumsq,
                                                       float* __restrict__ zptr, int zcount) {
    int c = threadIdx.x;  // 512
    int b = blockIdx.x;   // 64
    for (int i = b * 512 + c; i < zcount; i += 64 * 512) zptr[i] = 0.f;
    float sm = 0.f, sq = 0.f;
    for (int r = b; r < NNODES; r += 64) {
        float v = h[(size_t)r * 512 + c];
        sm += v;
        sq += v * v;
    }
    psum[b * 512 + c] = sm;
    psumsq[b * 512 + c] = sq;
}

__global__ __launch_bounds__(512) void bn_finalize_kernel(const float* __restrict__ psum,
                                                          const float* __restrict__ psumsq,
                                                          const float* __restrict__ gamma,
                                                          const float* __restrict__ beta,
                                                          float* __restrict__ scale,
                                                          float* __restrict__ shift) {
    int c = threadIdx.x;
    float sm = 0.f, sq = 0.f;
    for (int b = 0; b < 64; ++b) {
        sm += psum[b * 512 + c];
        sq += psumsq[b * 512 + c];
    }
    const float invN = 1.0f / (float)NNODES;
    float mu = sm * invN;
    float var = sq * invN - mu * mu;
    float sc = gamma[c] * rsqrtf(var + BN_EPS);
    scale[c] = sc;
    shift[c] = beta[c] - mu * sc;
}

__global__ __launch_bounds__(256) void bn_apply_kernel(const float* __restrict__ h,
                                                       const float* __restrict__ scale,
                                                       const float* __restrict__ shift,
                                                       uint_t* __restrict__ hbf) {
    int t = threadIdx.x, b = blockIdx.x;   // grid = 256
    int c0 = t * 2, c1 = c0 + 1;
    float sc0 = scale[c0], sc1 = scale[c1];
    float sh0 = shift[c0], sh1 = shift[c1];
    for (int r = b; r < NNODES; r += 256) {
        float2 hv = ((const float2*)(h + (size_t)r * 512))[t];
        float v0 = hv.x * sc0 + sh0;
        float v1 = hv.y * sc1 + sh1;
        v0 = (v0 > 0.f) ? v0 : (__expf(v0) - 1.0f);
        v1 = (v1 > 0.f) ? v1 : (__expf(v1) - 1.0f);
        hbf[r * 256 + t] = ((uint_t)f2bf(v1) << 16) | (uint_t)f2bf(v0);
    }
}

// ---------------------------------------------------------------------------
// launch — 18 dispatches
// ---------------------------------------------------------------------------
extern "C" void kernel_launch(void* const* d_in, const int* in_sizes, int n_in,
                              void* d_out, int out_size, void* d_ws, size_t ws_size,
                              hipStream_t stream) {
    const float* x      = (const float*)d_in[0];
    const int*   ei     = (const int*)d_in[1];
    const float* W1     = (const float*)d_in[2];
    const float* a_src1 = (const float*)d_in[3];
    const float* a_dst1 = (const float*)d_in[4];
    const float* b1     = (const float*)d_in[5];
    const float* g1     = (const float*)d_in[6];
    const float* be1    = (const float*)d_in[7];
    const float* W2     = (const float*)d_in[8];
    const float* a_src2 = (const float*)d_in[9];
    const float* a_dst2 = (const float*)d_in[10];
    const float* b2     = (const float*)d_in[11];
    const float* g2     = (const float*)d_in[12];
    const float* be2    = (const float*)d_in[13];
    const float* W3     = (const float*)d_in[14];
    const float* a_src3 = (const float*)d_in[15];
    const float* a_dst3 = (const float*)d_in[16];
    const float* b3     = (const float*)d_in[17];
    float* out = (float*)d_out;

    const int* e_src = ei;           // edge_index[0]
    const int* e_dst = ei + NEDGES;  // edge_index[1]

    // ---- workspace layout ----
    char* w = (char*)d_ws;
    // region 0: x_bf (25.6 MB), later reused as hbuf fp32 (20.48 MB) + ew (5.12 MB)
    ushort_t* x_bf = (ushort_t*)w;
    float*    hbuf = (float*)w;                               // alias after L1 GEMM
    float*    ew   = (float*)(w + (size_t)NNODES * HC_ * sizeof(float));  // tail 5.12 MB
    w += (size_t)NNODES * INF_ * sizeof(ushort_t);            // 25.6 MB
    uint_t* xpb = (uint_t*)w;  w += (size_t)NNODES * HC_ * sizeof(ushort_t);
    uint_t* hbf = (uint_t*)w;  w += (size_t)NNODES * HC_ * sizeof(ushort_t);
    ushort_t* Wt1 = (ushort_t*)w; w += (size_t)HC_ * INF_ * sizeof(ushort_t);
    ushort_t* Wt2 = (ushort_t*)w; w += (size_t)HC_ * HC_ * sizeof(ushort_t);
    ushort_t* Wt3 = (ushort_t*)w; w += (size_t)HC_ * HC_ * sizeof(ushort_t);
    // counts | s_log | d_log contiguous -> single zero pass
    int* counts  = (int*)w;    w += NNODES * sizeof(int);
    float* s_log = (float*)w;  w += NNODES * HEADS_ * sizeof(float);
    float* d_log = (float*)w;  w += NNODES * HEADS_ * sizeof(float);
    float* bnscale = (float*)w; w += HC_ * sizeof(float);
    float* bnshift = (float*)w; w += HC_ * sizeof(float);
    float* psum  = (float*)w;  w += 64 * HC_ * sizeof(float);
    float* psumsq= (float*)w;  w += 64 * HC_ * sizeof(float);
    int* offsets = (int*)w;    w += (NNODES + 1) * sizeof(int);
    int* cursor  = (int*)w;    w += NNODES * sizeof(int);
    int* esrc    = (int*)w;    w += NEDGES * sizeof(int);
    int* bsum    = (int*)w;    w += 64 * sizeof(int);

    dim3 gg(HC_ / 64, (NNODES + 63) / 64);           // (8, 157) plain 2-D grid
    const int aggGrid = (NNODES + 3) / 4;            // 2500
    const int scanBlocks = (NNODES + 255) / 256;     // 40

    zero_kernel<<<64, 256, 0, stream>>>((float*)counts, NNODES + 2 * NNODES * HEADS_);
    count_kernel<<<(NEDGES + 255) / 256, 256, 0, stream>>>(e_dst, counts, NEDGES);
    scan1_kernel<<<scanBlocks, 256, 0, stream>>>(counts, offsets, bsum, NNODES);
    scan3b_kernel<<<scanBlocks, 256, 0, stream>>>(offsets, cursor, bsum, scanBlocks, NNODES);
    scatter_kernel<<<(NEDGES + 255) / 256, 256, 0, stream>>>(e_src, e_dst, cursor, esrc, NEDGES);
    {
        int TOT = CVX + CN1 + CN2 + CN3;
        convall_kernel<<<(TOT + 255) / 256, 256, 0, stream>>>(x, W1, W2, W3, x_bf, Wt1, Wt2, Wt3);
    }

    // ---- Layer 1 ----   (x_bf dead after its GEMM; hbuf/ew alias its region)
    gemm_fused_kernel<<<gg, 256, 0, stream>>>(x_bf, Wt1, (ushort_t*)xpb,
        a_src1, a_dst1, s_log, d_log, NNODES, INF_, HC_, HEADS_);
    softagg_kernel<HEADS_><<<aggGrid, 256, 0, stream>>>((const uint4*)xpb, s_log, d_log,
        offsets, esrc, ew, b1, hbuf, HC_, HC_);
    bn_stats_kernel<<<64, 512, 0, stream>>>(hbuf, psum, psumsq, s_log, 2 * NNODES * HEADS_);
    bn_finalize_kernel<<<1, 512, 0, stream>>>(psum, psumsq, g1, be1, bnscale, bnshift);
    bn_apply_kernel<<<256, 256, 0, stream>>>(hbuf, bnscale, bnshift, hbf);

    // ---- Layer 2 ----
    gemm_fused_kernel<<<gg, 256, 0, stream>>>((const ushort_t*)hbf, Wt2, (ushort_t*)xpb,
        a_src2, a_dst2, s_log, d_log, NNODES, HC_, HC_, HEADS_);
    softagg_kernel<HEADS_><<<aggGrid, 256, 0, stream>>>((const uint4*)xpb, s_log, d_log,
        offsets, esrc, ew, b2, hbuf, HC_, HC_);
    bn_stats_kernel<<<64, 512, 0, stream>>>(hbuf, psum, psumsq, s_log, 2 * NNODES * HEADS_);
    bn_finalize_kernel<<<1, 512, 0, stream>>>(psum, psumsq, g2, be2, bnscale, bnshift);
    bn_apply_kernel<<<256, 256, 0, stream>>>(hbuf, bnscale, bnshift, hbf);

    // ---- Layer 3 (H=1, N=500) ----
    gemm_fused_kernel<<<gg, 256, 0, stream>>>((const ushort_t*)hbf, Wt3, (ushort_t*)xpb,
        a_src3, a_dst3, s_log, d_log, NNODES, HC_, OUTF_, 1);
    softagg_kernel<1><<<aggGrid, 256, 0, stream>>>((const uint4*)xpb, s_log, d_log,
        offsets, esrc, ew, b3, out, OUTF_, OUTF_);
}

// Round 12
// 512.765 us; speedup vs baseline: 1.0235x; 1.0235x over previous
//
#include <hip/hip_runtime.h>
#include <hip/hip_bf16.h>

// Problem constants (from reference)
#define NNODES 10000
#define NEDGES 320000
#define INF_   1280
#define HID_   128
#define HEADS_ 4
#define OUTF_  500
#define HC_    512          // HEADS_*HID_
#define NEG_SLOPE 0.2f
#define BN_EPS 1e-5f

typedef __attribute__((ext_vector_type(8))) short short8x;
typedef __attribute__((ext_vector_type(4))) float f32x4;
typedef unsigned short ushort_t;
typedef unsigned int uint_t;

__device__ __forceinline__ ushort_t f2bf(float f) {
    uint_t u = __float_as_uint(f);
    u = (u + 0x7fffu + ((u >> 16) & 1u)) >> 16;   // round-to-nearest-even
    return (ushort_t)u;
}
__device__ __forceinline__ float bf_lo(uint_t p) { return __uint_as_float(p << 16); }
__device__ __forceinline__ float bf_hi(uint_t p) { return __uint_as_float(p & 0xffff0000u); }
__device__ __forceinline__ float lrelu(float x) { return (x >= 0.f) ? x : NEG_SLOPE * x; }
__device__ __forceinline__ uint_t pack_bf16_rn(float a, float b) {
    __hip_bfloat162 h = __float22bfloat162_rn(make_float2(a, b));  // hw packed cvt, RNE
    return *(uint_t*)&h;
}

// ---------------------------------------------------------------------------
// utility
// ---------------------------------------------------------------------------
__global__ void zero_kernel(float* __restrict__ p, size_t n) {
    size_t i = (size_t)blockIdx.x * blockDim.x + threadIdx.x;
    size_t stride = (size_t)gridDim.x * blockDim.x;
    for (; i < n; i += stride) p[i] = 0.0f;
}

// one kernel: x->bf16 (vectorized) + 3 weight transposes
#define CVX (NNODES * INF_ / 4)        // 3,200,000 float4 chunks of x
#define CN1 (HC_ * INF_)
#define CN2 (HC_ * HC_)
#define CN3 (HC_ * HC_)                // Wt3 (padded rows)
__global__ void convall_kernel(const float* __restrict__ x,
                               const float* __restrict__ W1,
                               const float* __restrict__ W2,
                               const float* __restrict__ W3,
                               ushort_t* __restrict__ x_bf,
                               ushort_t* __restrict__ Wt1,
                               ushort_t* __restrict__ Wt2,
                               ushort_t* __restrict__ Wt3) {
    int i = blockIdx.x * blockDim.x + threadIdx.x;
    if (i < CVX) {
        float4 v = ((const float4*)x)[i];
        ((uint2*)x_bf)[i] = make_uint2(pack_bf16_rn(v.x, v.y), pack_bf16_rn(v.z, v.w));
    } else if (i < CVX + CN1) {
        int j = i - CVX;
        int n = j / INF_, k = j - n * INF_;
        Wt1[j] = f2bf(W1[(size_t)k * HC_ + n]);
    } else if (i < CVX + CN1 + CN2) {
        int j = i - CVX - CN1;
        int n = j / HC_, k = j - n * HC_;
        Wt2[j] = f2bf(W2[(size_t)k * HC_ + n]);
    } else if (i < CVX + CN1 + CN2 + CN3) {
        int j = i - CVX - CN1 - CN2;
        int n = j / HC_, k = j - n * HC_;
        Wt3[j] = (n < OUTF_) ? f2bf(W3[(size_t)k * OUTF_ + n]) : (ushort_t)0;
    }
}

// ---------------------------------------------------------------------------
// CSR build (by destination)
// ---------------------------------------------------------------------------
__global__ void count_kernel(const int* __restrict__ dst, int* __restrict__ counts, int E) {
    int e = blockIdx.x * blockDim.x + threadIdx.x;
    if (e < E) atomicAdd(&counts[dst[e]], 1);
}

__global__ __launch_bounds__(256) void scan1_kernel(const int* __restrict__ counts,
                                                    int* __restrict__ offsets,
                                                    int* __restrict__ bsum, int n) {
    __shared__ int tmp[256];
    int b = blockIdx.x, t = threadIdx.x;
    int i = b * 256 + t;
    int v = (i < n) ? counts[i] : 0;
    tmp[t] = v;
    __syncthreads();
    for (int off = 1; off < 256; off <<= 1) {
        int u = (t >= off) ? tmp[t - off] : 0;
        __syncthreads();
        tmp[t] += u;
        __syncthreads();
    }
    if (i < n) offsets[i] = tmp[t] - v;
    if (t == 255) bsum[b] = tmp[t];
}

__global__ __launch_bounds__(256) void scan3b_kernel(int* __restrict__ offsets,
                                                     int* __restrict__ cursor,
                                                     const int* __restrict__ bsum,
                                                     int nb, int n) {
    __shared__ int base_sh, tot_sh;
    int b = blockIdx.x, t = threadIdx.x;
    if (t == 0) {
        int acc = 0, tot = 0;
        for (int k = 0; k < nb; ++k) { if (k < b) acc += bsum[k]; tot += bsum[k]; }
        base_sh = acc; tot_sh = tot;
    }
    __syncthreads();
    int i = b * 256 + t;
    if (i < n) {
        int v = offsets[i] + base_sh;
        offsets[i] = v;
        cursor[i] = v;
    }
    if (b == nb - 1 && t == 0) offsets[n] = tot_sh;
}

__global__ void scatter_kernel(const int* __restrict__ src, const int* __restrict__ dst,
                               int* __restrict__ cursor, int* __restrict__ esrc, int E) {
    int e = blockIdx.x * blockDim.x + threadIdx.x;
    if (e < E) {
        int p = atomicAdd(&cursor[dst[e]], 1);
        esrc[p] = src[e];
    }
}

// ---------------------------------------------------------------------------
// PURE bf16 MFMA GEMM (R4 config — the empirically fastest: 64x64, BK=32,
// plain 2-D grid, no epilogue extras). C row stride fixed 512, Bt padded.
// ---------------------------------------------------------------------------
#define LDT 40

__global__ __launch_bounds__(256) void gemm_kernel(
    const ushort_t* __restrict__ A,    // [M][K] bf16
    const ushort_t* __restrict__ Bt,   // [512][K] bf16 (transposed, padded)
    ushort_t* __restrict__ Cb,         // [M][512] bf16
    int M, int K)
{
    __shared__ __align__(16) ushort_t As[64 * LDT];
    __shared__ __align__(16) ushort_t Bs[64 * LDT];

    int m0 = blockIdx.y * 64;
    int n0 = blockIdx.x * 64;

    int tid  = threadIdx.x;
    int lane = tid & 63;
    int w    = tid >> 6;
    int wm   = (w & 1) * 32;
    int wn   = (w >> 1) * 32;
    int quad = lane >> 4;
    int c16  = lane & 15;

    f32x4 acc[2][2];
#pragma unroll
    for (int i = 0; i < 2; ++i)
#pragma unroll
        for (int j = 0; j < 2; ++j)
#pragma unroll
            for (int r = 0; r < 4; ++r) acc[i][j][r] = 0.0f;

    int sr = tid >> 2;
    int sk = (tid & 3) * 8;

    for (int k0 = 0; k0 < K; k0 += 32) {
        int gm = m0 + sr;
        if (gm > M - 1) gm = M - 1;
        uint4 av = *(const uint4*)(A + (size_t)gm * K + k0 + sk);
        *(uint4*)&As[sr * LDT + sk] = av;

        uint4 bv = *(const uint4*)(Bt + (size_t)(n0 + sr) * K + k0 + sk);
        *(uint4*)&Bs[sr * LDT + sk] = bv;
        __syncthreads();

        short8x af0 = *(const short8x*)&As[(wm +      c16) * LDT + quad * 8];
        short8x af1 = *(const short8x*)&As[(wm + 16 + c16) * LDT + quad * 8];
        short8x bf0 = *(const short8x*)&Bs[(wn +      c16) * LDT + quad * 8];
        short8x bf1 = *(const short8x*)&Bs[(wn + 16 + c16) * LDT + quad * 8];

        acc[0][0] = __builtin_amdgcn_mfma_f32_16x16x32_bf16(af0, bf0, acc[0][0], 0, 0, 0);
        acc[0][1] = __builtin_amdgcn_mfma_f32_16x16x32_bf16(af0, bf1, acc[0][1], 0, 0, 0);
        acc[1][0] = __builtin_amdgcn_mfma_f32_16x16x32_bf16(af1, bf0, acc[1][0], 0, 0, 0);
        acc[1][1] = __builtin_amdgcn_mfma_f32_16x16x32_bf16(af1, bf1, acc[1][1], 0, 0, 0);
        __syncthreads();
    }

#pragma unroll
    for (int mt = 0; mt < 2; ++mt) {
#pragma unroll
        for (int r = 0; r < 4; ++r) {
            int row = m0 + wm + mt * 16 + quad * 4 + r;
            if (row < M) {
                int col0 = n0 + wn + c16;
                Cb[(size_t)row * 512 + col0]      = f2bf(acc[mt][0][r]);
                Cb[(size_t)row * 512 + col0 + 16] = f2bf(acc[mt][1][r]);
            }
        }
    }
}

// ---------------------------------------------------------------------------
// logits: one wave per node (4 nodes/block). Lane l owns channels [8l, 8l+8)
// of the node's 512-wide row — exactly head l>>4 for H=4. shfl-reduce.
// ---------------------------------------------------------------------------
template<int H>
__global__ __launch_bounds__(256) void logits_kernel(
    const uint4* __restrict__ xpb4,    // [node][64]
    const float* __restrict__ aS, const float* __restrict__ aD,
    float* __restrict__ s_log, float* __restrict__ d_log, int OUTC)
{
    int node = blockIdx.x * 4 + (threadIdx.x >> 6);
    if (node >= NNODES) return;
    int lane = threadIdx.x & 63;
    uint4 p = xpb4[(size_t)node * 64 + lane];
    float xv[8] = {bf_lo(p.x), bf_hi(p.x), bf_lo(p.y), bf_hi(p.y),
                   bf_lo(p.z), bf_hi(p.z), bf_lo(p.w), bf_hi(p.w)};
    int cbase = lane * 8;
    float sv = 0.f, dv = 0.f;
    if (cbase + 7 < OUTC) {
        float4 a0 = ((const float4*)aS)[lane * 2];
        float4 a1 = ((const float4*)aS)[lane * 2 + 1];
        float4 b0 = ((const float4*)aD)[lane * 2];
        float4 b1 = ((const float4*)aD)[lane * 2 + 1];
        sv = xv[0]*a0.x + xv[1]*a0.y + xv[2]*a0.z + xv[3]*a0.w
           + xv[4]*a1.x + xv[5]*a1.y + xv[6]*a1.z + xv[7]*a1.w;
        dv = xv[0]*b0.x + xv[1]*b0.y + xv[2]*b0.z + xv[3]*b0.w
           + xv[4]*b1.x + xv[5]*b1.y + xv[6]*b1.z + xv[7]*b1.w;
    } else {
#pragma unroll
        for (int k = 0; k < 8; ++k) {
            int c = cbase + k;
            if (c < OUTC) { sv += xv[k] * aS[c]; dv += xv[k] * aD[c]; }
        }
    }
    int grp = (H == 4) ? 16 : 64;
    for (int off = 1; off < grp; off <<= 1) {
        sv += __shfl_xor(sv, off);
        dv += __shfl_xor(dv, off);
    }
    if ((lane & (grp - 1)) == 0) {
        int h = (H == 4) ? (lane >> 4) : 0;
        s_log[node * H + h] = sv;
        d_log[node * H + h] = dv;
    }
}

// ---------------------------------------------------------------------------
// softagg2: ONE NODE PER 256-THREAD BLOCK. Softmax phases stride edges over
// all 256 threads (LDS reduce); gather splits edges mod 4 across the 4
// waves (quarters the per-node serial chain); partials combined via LDS.
// ---------------------------------------------------------------------------
__device__ __forceinline__ void acc8(float* acc, uint4 q, float w) {
    acc[0] += w * bf_lo(q.x); acc[1] += w * bf_hi(q.x);
    acc[2] += w * bf_lo(q.y); acc[3] += w * bf_hi(q.y);
    acc[4] += w * bf_lo(q.z); acc[5] += w * bf_hi(q.z);
    acc[6] += w * bf_lo(q.w); acc[7] += w * bf_hi(q.w);
}

template<int H>
__global__ __launch_bounds__(256) void softagg2_kernel(
    const uint4* __restrict__ xpb4,     // [node][64] (512 bf16 / row)
    const float* __restrict__ s,        // [node][H]
    const float* __restrict__ dlog,     // [node][H]
    const int* __restrict__ offsets, const int* __restrict__ esrc,
    float* __restrict__ ew,             // [E][H] scratch
    const float* __restrict__ bias,     // [OUTC]
    float* __restrict__ out,            // [node][ldo]
    int OUTC, int ldo)
{
    __shared__ float red[4][H];         // per-wave partials
    __shared__ float mfull[H], wselfS[H], zinvS[H];
    __shared__ float accS[3][64][9];    // waves 1..3 acc partials (+1 pad)

    int node = blockIdx.x;
    int tid = threadIdx.x;
    int w = tid >> 6;
    int lane = tid & 63;
    int e0 = offsets[node], e1 = offsets[node + 1];

    float dh[H], selfe[H], mh[H];
#pragma unroll
    for (int h = 0; h < H; ++h) {
        dh[h] = dlog[node * H + h];
        selfe[h] = lrelu(s[node * H + h] + dh[h]);
        mh[h] = selfe[h];
    }

    // ---- phase 1: max over edges (256-thread stride) ----
    for (int j = e0 + tid; j < e1; j += 256) {
        int src = esrc[j];
        if (H == 4) {
            float4 sv = ((const float4*)s)[src];
            mh[0] = fmaxf(mh[0], lrelu(sv.x + dh[0]));
            mh[1] = fmaxf(mh[1], lrelu(sv.y + dh[1]));
            mh[2] = fmaxf(mh[2], lrelu(sv.z + dh[2]));
            mh[3] = fmaxf(mh[3], lrelu(sv.w + dh[3]));
        } else {
            mh[0] = fmaxf(mh[0], lrelu(s[src] + dh[0]));
        }
    }
#pragma unroll
    for (int h = 0; h < H; ++h)
        for (int off = 32; off > 0; off >>= 1)
            mh[h] = fmaxf(mh[h], __shfl_xor(mh[h], off));
    if (lane == 0) {
#pragma unroll
        for (int h = 0; h < H; ++h) red[w][h] = mh[h];
    }
    __syncthreads();
    if (tid < H) {
        float m = red[0][tid];
        m = fmaxf(m, red[1][tid]); m = fmaxf(m, red[2][tid]); m = fmaxf(m, red[3][tid]);
        mfull[tid] = m;
    }
    __syncthreads();
#pragma unroll
    for (int h = 0; h < H; ++h) mh[h] = mfull[h];

    // ---- phase 2: exp weights + z (256-thread stride) ----
    float zh[H];
#pragma unroll
    for (int h = 0; h < H; ++h) zh[h] = 0.f;
    for (int j = e0 + tid; j < e1; j += 256) {
        int src = esrc[j];
        if (H == 4) {
            float4 sv = ((const float4*)s)[src];
            float w0 = __expf(lrelu(sv.x + dh[0]) - mh[0]);
            float w1 = __expf(lrelu(sv.y + dh[1]) - mh[1]);
            float w2 = __expf(lrelu(sv.z + dh[2]) - mh[2]);
            float w3 = __expf(lrelu(sv.w + dh[3]) - mh[3]);
            ((float4*)ew)[j] = make_float4(w0, w1, w2, w3);
            zh[0] += w0; zh[1] += w1; zh[2] += w2; zh[3] += w3;
        } else {
            float w0 = __expf(lrelu(s[src] + dh[0]) - mh[0]);
            ew[j] = w0;
            zh[0] += w0;
        }
    }
#pragma unroll
    for (int h = 0; h < H; ++h)
        for (int off = 32; off > 0; off >>= 1)
            zh[h] += __shfl_xor(zh[h], off);
    __syncthreads();   // red[] reuse
    if (lane == 0) {
#pragma unroll
        for (int h = 0; h < H; ++h) red[w][h] = zh[h];
    }
    __syncthreads();
    if (tid < H) {
        float z = red[0][tid] + red[1][tid] + red[2][tid] + red[3][tid];
        float ws = __expf(selfe[tid] - mfull[tid]);
        wselfS[tid] = ws;
        zinvS[tid] = 1.0f / (z + ws);
    }
    __syncthreads();

    // ---- phase 3: gather; wave w takes edges (j-e0)%4 == w ----
    int hg = (H == 4) ? (lane >> 4) : 0;
    float acc[8];
    if (w == 0) {
        float ws = wselfS[hg];
        uint4 p = xpb4[(size_t)node * 64 + lane];
        acc[0] = ws * bf_lo(p.x); acc[1] = ws * bf_hi(p.x);
        acc[2] = ws * bf_lo(p.y); acc[3] = ws * bf_hi(p.y);
        acc[4] = ws * bf_lo(p.z); acc[5] = ws * bf_hi(p.z);
        acc[6] = ws * bf_lo(p.w); acc[7] = ws * bf_hi(p.w);
    } else {
#pragma unroll
        for (int k = 0; k < 8; ++k) acc[k] = 0.f;
    }

    int j = e0 + w;
    for (; j + 12 < e1; j += 16) {
        int s0 = esrc[j], s1 = esrc[j + 4], s2 = esrc[j + 8], s3 = esrc[j + 12];
        float w0 = ew[(size_t)j * H + hg];
        float w1 = ew[(size_t)(j + 4) * H + hg];
        float w2 = ew[(size_t)(j + 8) * H + hg];
        float w3 = ew[(size_t)(j + 12) * H + hg];
        uint4 q0 = xpb4[(size_t)s0 * 64 + lane];
        uint4 q1 = xpb4[(size_t)s1 * 64 + lane];
        uint4 q2 = xpb4[(size_t)s2 * 64 + lane];
        uint4 q3 = xpb4[(size_t)s3 * 64 + lane];
        acc8(acc, q0, w0);
        acc8(acc, q1, w1);
        acc8(acc, q2, w2);
        acc8(acc, q3, w3);
    }
    for (; j < e1; j += 4) {
        int s0 = esrc[j];
        float w0 = ew[(size_t)j * H + hg];
        uint4 q0 = xpb4[(size_t)s0 * 64 + lane];
        acc8(acc, q0, w0);
    }

    // ---- phase 4: combine across waves ----
    if (w > 0) {
#pragma unroll
        for (int k = 0; k < 8; ++k) accS[w - 1][lane][k] = acc[k];
    }
    __syncthreads();
    if (w == 0) {
#pragma unroll
        for (int w2 = 0; w2 < 3; ++w2)
#pragma unroll
            for (int k = 0; k < 8; ++k) acc[k] += accS[w2][lane][k];

        float zi = zinvS[hg];
        int cbase = lane * 8;
        size_t ob = (size_t)node * ldo + cbase;
        if (cbase + 7 < OUTC) {
            float4 o0 = make_float4(acc[0] * zi + bias[cbase + 0], acc[1] * zi + bias[cbase + 1],
                                    acc[2] * zi + bias[cbase + 2], acc[3] * zi + bias[cbase + 3]);
            float4 o1 = make_float4(acc[4] * zi + bias[cbase + 4], acc[5] * zi + bias[cbase + 5],
                                    acc[6] * zi + bias[cbase + 6], acc[7] * zi + bias[cbase + 7]);
            *(float4*)(out + ob) = o0;
            *(float4*)(out + ob + 4) = o1;
        } else {
#pragma unroll
            for (int k = 0; k < 8; ++k) {
                int c = cbase + k;
                if (c < OUTC) out[ob + k] = acc[k] * zi + bias[c];
            }
        }
    }
}

// ---------------------------------------------------------------------------
// BatchNorm: stats (64-block partials) -> tiny finalize -> wide apply+pack.
// ---------------------------------------------------------------------------
__global__ __launch_bounds__(512) void bn_stats_kernel(const float* __restrict__ h,
                                                       float* __restrict__ psum,
                                                       float* __restrict__ psumsq) {
    int c = threadIdx.x;  // 512
    int b = blockIdx.x;   // 64
    float sm = 0.f, sq = 0.f;
    for (int r = b; r < NNODES; r += 64) {
        float v = h[(size_t)r * 512 + c];
        sm += v;
        sq += v * v;
    }
    psum[b * 512 + c] = sm;
    psumsq[b * 512 + c] = sq;
}

__global__ __launch_bounds__(512) void bn_finalize_kernel(const float* __restrict__ psum,
                                                          const float* __restrict__ psumsq,
                                                          const float* __restrict__ gamma,
                                                          const float* __restrict__ beta,
                                                          float* __restrict__ scale,
                                                          float* __restrict__ shift) {
    int c = threadIdx.x;
    float sm = 0.f, sq = 0.f;
    for (int b = 0; b < 64; ++b) {
        sm += psum[b * 512 + c];
        sq += psumsq[b * 512 + c];
    }
    const float invN = 1.0f / (float)NNODES;
    float mu = sm * invN;
    float var = sq * invN - mu * mu;
    float sc = gamma[c] * rsqrtf(var + BN_EPS);
    scale[c] = sc;
    shift[c] = beta[c] - mu * sc;
}

__global__ __launch_bounds__(256) void bn_apply_kernel(const float* __restrict__ h,
                                                       const float* __restrict__ scale,
                                                       const float* __restrict__ shift,
                                                       uint_t* __restrict__ hbf) {
    int t = threadIdx.x, b = blockIdx.x;   // grid = 256
    int c0 = t * 2, c1 = c0 + 1;
    float sc0 = scale[c0], sc1 = scale[c1];
    float sh0 = shift[c0], sh1 = shift[c1];
    for (int r = b; r < NNODES; r += 256) {
        float2 hv = ((const float2*)(h + (size_t)r * 512))[t];
        float v0 = hv.x * sc0 + sh0;
        float v1 = hv.y * sc1 + sh1;
        v0 = (v0 > 0.f) ? v0 : (__expf(v0) - 1.0f);
        v1 = (v1 > 0.f) ? v1 : (__expf(v1) - 1.0f);
        hbf[r * 256 + t] = ((uint_t)f2bf(v1) << 16) | (uint_t)f2bf(v0);
    }
}

// ---------------------------------------------------------------------------
// launch — 21 dispatches
// ---------------------------------------------------------------------------
extern "C" void kernel_launch(void* const* d_in, const int* in_sizes, int n_in,
                              void* d_out, int out_size, void* d_ws, size_t ws_size,
                              hipStream_t stream) {
    const float* x      = (const float*)d_in[0];
    const int*   ei     = (const int*)d_in[1];
    const float* W1     = (const float*)d_in[2];
    const float* a_src1 = (const float*)d_in[3];
    const float* a_dst1 = (const float*)d_in[4];
    const float* b1     = (const float*)d_in[5];
    const float* g1     = (const float*)d_in[6];
    const float* be1    = (const float*)d_in[7];
    const float* W2     = (const float*)d_in[8];
    const float* a_src2 = (const float*)d_in[9];
    const float* a_dst2 = (const float*)d_in[10];
    const float* b2     = (const float*)d_in[11];
    const float* g2     = (const float*)d_in[12];
    const float* be2    = (const float*)d_in[13];
    const float* W3     = (const float*)d_in[14];
    const float* a_src3 = (const float*)d_in[15];
    const float* a_dst3 = (const float*)d_in[16];
    const float* b3     = (const float*)d_in[17];
    float* out = (float*)d_out;

    const int* e_src = ei;           // edge_index[0]
    const int* e_dst = ei + NEDGES;  // edge_index[1]

    // ---- workspace layout ----
    char* w = (char*)d_ws;
    ushort_t* x_bf = (ushort_t*)w;
    float*    hbuf = (float*)w;                               // alias after L1 GEMM
    float*    ew   = (float*)(w + (size_t)NNODES * HC_ * sizeof(float));  // tail 5.12 MB
    w += (size_t)NNODES * INF_ * sizeof(ushort_t);            // 25.6 MB
    uint_t* xpb = (uint_t*)w;  w += (size_t)NNODES * HC_ * sizeof(ushort_t);
    uint_t* hbf = (uint_t*)w;  w += (size_t)NNODES * HC_ * sizeof(ushort_t);
    ushort_t* Wt1 = (ushort_t*)w; w += (size_t)HC_ * INF_ * sizeof(ushort_t);
    ushort_t* Wt2 = (ushort_t*)w; w += (size_t)HC_ * HC_ * sizeof(ushort_t);
    ushort_t* Wt3 = (ushort_t*)w; w += (size_t)HC_ * HC_ * sizeof(ushort_t);
    int* counts  = (int*)w;    w += NNODES * sizeof(int);
    float* s_log = (float*)w;  w += NNODES * HEADS_ * sizeof(float);
    float* d_log = (float*)w;  w += NNODES * HEADS_ * sizeof(float);
    float* bnscale = (float*)w; w += HC_ * sizeof(float);
    float* bnshift = (float*)w; w += HC_ * sizeof(float);
    float* psum  = (float*)w;  w += 64 * HC_ * sizeof(float);
    float* psumsq= (float*)w;  w += 64 * HC_ * sizeof(float);
    int* offsets = (int*)w;    w += (NNODES + 1) * sizeof(int);
    int* cursor  = (int*)w;    w += NNODES * sizeof(int);
    int* esrc    = (int*)w;    w += NEDGES * sizeof(int);
    int* bsum    = (int*)w;    w += 64 * sizeof(int);

    dim3 gg(HC_ / 64, (NNODES + 63) / 64);           // (8, 157) plain 2-D grid
    const int lgGrid = (NNODES + 3) / 4;             // 2500 (logits)
    const int scanBlocks = (NNODES + 255) / 256;     // 40

    zero_kernel<<<32, 256, 0, stream>>>((float*)counts, NNODES);
    count_kernel<<<(NEDGES + 255) / 256, 256, 0, stream>>>(e_dst, counts, NEDGES);
    scan1_kernel<<<scanBlocks, 256, 0, stream>>>(counts, offsets, bsum, NNODES);
    scan3b_kernel<<<scanBlocks, 256, 0, stream>>>(offsets, cursor, bsum, scanBlocks, NNODES);
    scatter_kernel<<<(NEDGES + 255) / 256, 256, 0, stream>>>(e_src, e_dst, cursor, esrc, NEDGES);
    {
        int TOT = CVX + CN1 + CN2 + CN3;
        convall_kernel<<<(TOT + 255) / 256, 256, 0, stream>>>(x, W1, W2, W3, x_bf, Wt1, Wt2, Wt3);
    }

    // ---- Layer 1 ----
    gemm_kernel<<<gg, 256, 0, stream>>>(x_bf, Wt1, (ushort_t*)xpb, NNODES, INF_);
    logits_kernel<HEADS_><<<lgGrid, 256, 0, stream>>>((const uint4*)xpb, a_src1, a_dst1, s_log, d_log, HC_);
    softagg2_kernel<HEADS_><<<NNODES, 256, 0, stream>>>((const uint4*)xpb, s_log, d_log,
        offsets, esrc, ew, b1, hbuf, HC_, HC_);
    bn_stats_kernel<<<64, 512, 0, stream>>>(hbuf, psum, psumsq);
    bn_finalize_kernel<<<1, 512, 0, stream>>>(psum, psumsq, g1, be1, bnscale, bnshift);
    bn_apply_kernel<<<256, 256, 0, stream>>>(hbuf, bnscale, bnshift, hbf);

    // ---- Layer 2 ----
    gemm_kernel<<<gg, 256, 0, stream>>>((const ushort_t*)hbf, Wt2, (ushort_t*)xpb, NNODES, HC_);
    logits_kernel<HEADS_><<<lgGrid, 256, 0, stream>>>((const uint4*)xpb, a_src2, a_dst2, s_log, d_log, HC_);
    softagg2_kernel<HEADS_><<<NNODES, 256, 0, stream>>>((const uint4*)xpb, s_log, d_log,
        offsets, esrc, ew, b2, hbuf, HC_, HC_);
    bn_stats_kernel<<<64, 512, 0, stream>>>(hbuf, psum, psumsq);
    bn_finalize_kernel<<<1, 512, 0, stream>>>(psum, psumsq, g2, be2, bnscale, bnshift);
    bn_apply_kernel<<<256, 256, 0, stream>>>(hbuf, bnscale, bnshift, hbf);

    // ---- Layer 3 (H=1, N=500) ----
    gemm_kernel<<<gg, 256, 0, stream>>>((const ushort_t*)hbf, Wt3, (ushort_t*)xpb, NNODES, HC_);
    logits_kernel<1><<<lgGrid, 256, 0, stream>>>((const uint4*)xpb, a_src3, a_dst3, s_log, d_log, OUTF_);
    softagg2_kernel<1><<<NNODES, 256, 0, stream>>>((const uint4*)xpb, s_log, d_log,
        offsets, esrc, ew, b3, out, OUTF_, OUTF_);
}

// Round 13
// 499.184 us; speedup vs baseline: 1.0514x; 1.0272x over previous
//
#include <hip/hip_runtime.h>
#include <hip/hip_bf16.h>

// Problem constants (from reference)
#define NNODES 10000
#define NEDGES 320000
#define INF_   1280
#define HID_   128
#define HEADS_ 4
#define OUTF_  500
#define HC_    512          // HEADS_*HID_
#define NEG_SLOPE 0.2f
#define BN_EPS 1e-5f

typedef __attribute__((ext_vector_type(8))) short short8x;
typedef __attribute__((ext_vector_type(4))) float f32x4;
typedef unsigned short ushort_t;
typedef unsigned int uint_t;

__device__ __forceinline__ ushort_t f2bf(float f) {
    uint_t u = __float_as_uint(f);
    u = (u + 0x7fffu + ((u >> 16) & 1u)) >> 16;   // round-to-nearest-even
    return (ushort_t)u;
}
__device__ __forceinline__ float bf_lo(uint_t p) { return __uint_as_float(p << 16); }
__device__ __forceinline__ float bf_hi(uint_t p) { return __uint_as_float(p & 0xffff0000u); }
__device__ __forceinline__ float lrelu(float x) { return (x >= 0.f) ? x : NEG_SLOPE * x; }
__device__ __forceinline__ uint_t pack_bf16_rn(float a, float b) {
    __hip_bfloat162 h = __float22bfloat162_rn(make_float2(a, b));  // hw packed cvt, RNE
    return *(uint_t*)&h;
}

// ---------------------------------------------------------------------------
// utility
// ---------------------------------------------------------------------------
__global__ void zero_kernel(float* __restrict__ p, size_t n) {
    size_t i = (size_t)blockIdx.x * blockDim.x + threadIdx.x;
    size_t stride = (size_t)gridDim.x * blockDim.x;
    for (; i < n; i += stride) p[i] = 0.0f;
}

// one kernel: x->bf16 (vectorized) + 3 weight transposes
#define CVX (NNODES * INF_ / 4)        // 3,200,000 float4 chunks of x
#define CN1 (HC_ * INF_)
#define CN2 (HC_ * HC_)
#define CN3 (HC_ * HC_)                // Wt3 (padded rows)
__global__ void convall_kernel(const float* __restrict__ x,
                               const float* __restrict__ W1,
                               const float* __restrict__ W2,
                               const float* __restrict__ W3,
                               ushort_t* __restrict__ x_bf,
                               ushort_t* __restrict__ Wt1,
                               ushort_t* __restrict__ Wt2,
                               ushort_t* __restrict__ Wt3) {
    int i = blockIdx.x * blockDim.x + threadIdx.x;
    if (i < CVX) {
        float4 v = ((const float4*)x)[i];
        ((uint2*)x_bf)[i] = make_uint2(pack_bf16_rn(v.x, v.y), pack_bf16_rn(v.z, v.w));
    } else if (i < CVX + CN1) {
        int j = i - CVX;
        int n = j / INF_, k = j - n * INF_;
        Wt1[j] = f2bf(W1[(size_t)k * HC_ + n]);
    } else if (i < CVX + CN1 + CN2) {
        int j = i - CVX - CN1;
        int n = j / HC_, k = j - n * HC_;
        Wt2[j] = f2bf(W2[(size_t)k * HC_ + n]);
    } else if (i < CVX + CN1 + CN2 + CN3) {
        int j = i - CVX - CN1 - CN2;
        int n = j / HC_, k = j - n * HC_;
        Wt3[j] = (n < OUTF_) ? f2bf(W3[(size_t)k * OUTF_ + n]) : (ushort_t)0;
    }
}

// ---------------------------------------------------------------------------
// CSR build (by destination)
// ---------------------------------------------------------------------------
__global__ void count_kernel(const int* __restrict__ dst, int* __restrict__ counts, int E) {
    int e = blockIdx.x * blockDim.x + threadIdx.x;
    if (e < E) atomicAdd(&counts[dst[e]], 1);
}

__global__ __launch_bounds__(256) void scan1_kernel(const int* __restrict__ counts,
                                                    int* __restrict__ offsets,
                                                    int* __restrict__ bsum, int n) {
    __shared__ int tmp[256];
    int b = blockIdx.x, t = threadIdx.x;
    int i = b * 256 + t;
    int v = (i < n) ? counts[i] : 0;
    tmp[t] = v;
    __syncthreads();
    for (int off = 1; off < 256; off <<= 1) {
        int u = (t >= off) ? tmp[t - off] : 0;
        __syncthreads();
        tmp[t] += u;
        __syncthreads();
    }
    if (i < n) offsets[i] = tmp[t] - v;
    if (t == 255) bsum[b] = tmp[t];
}

__global__ __launch_bounds__(256) void scan3b_kernel(int* __restrict__ offsets,
                                                     int* __restrict__ cursor,
                                                     const int* __restrict__ bsum,
                                                     int nb, int n) {
    __shared__ int base_sh, tot_sh;
    int b = blockIdx.x, t = threadIdx.x;
    if (t == 0) {
        int acc = 0, tot = 0;
        for (int k = 0; k < nb; ++k) { if (k < b) acc += bsum[k]; tot += bsum[k]; }
        base_sh = acc; tot_sh = tot;
    }
    __syncthreads();
    int i = b * 256 + t;
    if (i < n) {
        int v = offsets[i] + base_sh;
        offsets[i] = v;
        cursor[i] = v;
    }
    if (b == nb - 1 && t == 0) offsets[n] = tot_sh;
}

__global__ void scatter_kernel(const int* __restrict__ src, const int* __restrict__ dst,
                               int* __restrict__ cursor, int* __restrict__ esrc, int E) {
    int e = blockIdx.x * blockDim.x + threadIdx.x;
    if (e < E) {
        int p = atomicAdd(&cursor[dst[e]], 1);
        esrc[p] = src[e];
    }
}

// ---------------------------------------------------------------------------
// PURE bf16 MFMA GEMM (R4 config). C row stride fixed 512, Bt padded.
// ---------------------------------------------------------------------------
#define LDT 40

__global__ __launch_bounds__(256) void gemm_kernel(
    const ushort_t* __restrict__ A,    // [M][K] bf16
    const ushort_t* __restrict__ Bt,   // [512][K] bf16 (transposed, padded)
    ushort_t* __restrict__ Cb,         // [M][512] bf16
    int M, int K)
{
    __shared__ __align__(16) ushort_t As[64 * LDT];
    __shared__ __align__(16) ushort_t Bs[64 * LDT];

    int m0 = blockIdx.y * 64;
    int n0 = blockIdx.x * 64;

    int tid  = threadIdx.x;
    int lane = tid & 63;
    int w    = tid >> 6;
    int wm   = (w & 1) * 32;
    int wn   = (w >> 1) * 32;
    int quad = lane >> 4;
    int c16  = lane & 15;

    f32x4 acc[2][2];
#pragma unroll
    for (int i = 0; i < 2; ++i)
#pragma unroll
        for (int j = 0; j < 2; ++j)
#pragma unroll
            for (int r = 0; r < 4; ++r) acc[i][j][r] = 0.0f;

    int sr = tid >> 2;
    int sk = (tid & 3) * 8;

    for (int k0 = 0; k0 < K; k0 += 32) {
        int gm = m0 + sr;
        if (gm > M - 1) gm = M - 1;
        uint4 av = *(const uint4*)(A + (size_t)gm * K + k0 + sk);
        *(uint4*)&As[sr * LDT + sk] = av;

        uint4 bv = *(const uint4*)(Bt + (size_t)(n0 + sr) * K + k0 + sk);
        *(uint4*)&Bs[sr * LDT + sk] = bv;
        __syncthreads();

        short8x af0 = *(const short8x*)&As[(wm +      c16) * LDT + quad * 8];
        short8x af1 = *(const short8x*)&As[(wm + 16 + c16) * LDT + quad * 8];
        short8x bf0 = *(const short8x*)&Bs[(wn +      c16) * LDT + quad * 8];
        short8x bf1 = *(const short8x*)&Bs[(wn + 16 + c16) * LDT + quad * 8];

        acc[0][0] = __builtin_amdgcn_mfma_f32_16x16x32_bf16(af0, bf0, acc[0][0], 0, 0, 0);
        acc[0][1] = __builtin_amdgcn_mfma_f32_16x16x32_bf16(af0, bf1, acc[0][1], 0, 0, 0);
        acc[1][0] = __builtin_amdgcn_mfma_f32_16x16x32_bf16(af1, bf0, acc[1][0], 0, 0, 0);
        acc[1][1] = __builtin_amdgcn_mfma_f32_16x16x32_bf16(af1, bf1, acc[1][1], 0, 0, 0);
        __syncthreads();
    }

#pragma unroll
    for (int mt = 0; mt < 2; ++mt) {
#pragma unroll
        for (int r = 0; r < 4; ++r) {
            int row = m0 + wm + mt * 16 + quad * 4 + r;
            if (row < M) {
                int col0 = n0 + wn + c16;
                Cb[(size_t)row * 512 + col0]      = f2bf(acc[mt][0][r]);
                Cb[(size_t)row * 512 + col0 + 16] = f2bf(acc[mt][1][r]);
            }
        }
    }
}

// ---------------------------------------------------------------------------
// logits: one wave per node (4 nodes/block). Lane l owns channels [8l, 8l+8).
// ---------------------------------------------------------------------------
template<int H>
__global__ __launch_bounds__(256) void logits_kernel(
    const uint4* __restrict__ xpb4,    // [node][64]
    const float* __restrict__ aS, const float* __restrict__ aD,
    float* __restrict__ s_log, float* __restrict__ d_log, int OUTC)
{
    int node = blockIdx.x * 4 + (threadIdx.x >> 6);
    if (node >= NNODES) return;
    int lane = threadIdx.x & 63;
    uint4 p = xpb4[(size_t)node * 64 + lane];
    float xv[8] = {bf_lo(p.x), bf_hi(p.x), bf_lo(p.y), bf_hi(p.y),
                   bf_lo(p.z), bf_hi(p.z), bf_lo(p.w), bf_hi(p.w)};
    int cbase = lane * 8;
    float sv = 0.f, dv = 0.f;
    if (cbase + 7 < OUTC) {
        float4 a0 = ((const float4*)aS)[lane * 2];
        float4 a1 = ((const float4*)aS)[lane * 2 + 1];
        float4 b0 = ((const float4*)aD)[lane * 2];
        float4 b1 = ((const float4*)aD)[lane * 2 + 1];
        sv = xv[0]*a0.x + xv[1]*a0.y + xv[2]*a0.z + xv[3]*a0.w
           + xv[4]*a1.x + xv[5]*a1.y + xv[6]*a1.z + xv[7]*a1.w;
        dv = xv[0]*b0.x + xv[1]*b0.y + xv[2]*b0.z + xv[3]*b0.w
           + xv[4]*b1.x + xv[5]*b1.y + xv[6]*b1.z + xv[7]*b1.w;
    } else {
#pragma unroll
        for (int k = 0; k < 8; ++k) {
            int c = cbase + k;
            if (c < OUTC) { sv += xv[k] * aS[c]; dv += xv[k] * aD[c]; }
        }
    }
    int grp = (H == 4) ? 16 : 64;
    for (int off = 1; off < grp; off <<= 1) {
        sv += __shfl_xor(sv, off);
        dv += __shfl_xor(dv, off);
    }
    if ((lane & (grp - 1)) == 0) {
        int h = (H == 4) ? (lane >> 4) : 0;
        s_log[node * H + h] = sv;
        d_log[node * H + h] = dv;
    }
}

// ---------------------------------------------------------------------------
// edge softmax (wave-per-node, 4 nodes/block): writes ew + wself + zinv.
// ---------------------------------------------------------------------------
template<int H>
__global__ __launch_bounds__(256) void edge_softmax_kernel(
    const float* __restrict__ s, const float* __restrict__ dlog,
    const int* __restrict__ offsets, const int* __restrict__ esrc,
    float* __restrict__ ew, float* __restrict__ wself, float* __restrict__ zinv)
{
    int node = blockIdx.x * 4 + (threadIdx.x >> 6);
    if (node >= NNODES) return;
    int lane = threadIdx.x & 63;
    int e0 = offsets[node], e1 = offsets[node + 1];

    float dh[H], selfe[H], mh[H], zh[H];
#pragma unroll
    for (int h = 0; h < H; ++h) {
        dh[h] = dlog[node * H + h];
        selfe[h] = lrelu(s[node * H + h] + dh[h]);
        mh[h] = selfe[h];
        zh[h] = 0.f;
    }
    for (int j = e0 + lane; j < e1; j += 64) {
        int src = esrc[j];
        if (H == 4) {
            float4 sv = ((const float4*)s)[src];
            mh[0] = fmaxf(mh[0], lrelu(sv.x + dh[0]));
            mh[1] = fmaxf(mh[1], lrelu(sv.y + dh[1]));
            mh[2] = fmaxf(mh[2], lrelu(sv.z + dh[2]));
            mh[3] = fmaxf(mh[3], lrelu(sv.w + dh[3]));
        } else {
            mh[0] = fmaxf(mh[0], lrelu(s[src] + dh[0]));
        }
    }
#pragma unroll
    for (int h = 0; h < H; ++h)
        for (int off = 32; off > 0; off >>= 1)
            mh[h] = fmaxf(mh[h], __shfl_xor(mh[h], off));

    for (int j = e0 + lane; j < e1; j += 64) {
        int src = esrc[j];
        if (H == 4) {
            float4 sv = ((const float4*)s)[src];
            float w0 = __expf(lrelu(sv.x + dh[0]) - mh[0]);
            float w1 = __expf(lrelu(sv.y + dh[1]) - mh[1]);
            float w2 = __expf(lrelu(sv.z + dh[2]) - mh[2]);
            float w3 = __expf(lrelu(sv.w + dh[3]) - mh[3]);
            ((float4*)ew)[j] = make_float4(w0, w1, w2, w3);
            zh[0] += w0; zh[1] += w1; zh[2] += w2; zh[3] += w3;
        } else {
            float w0 = __expf(lrelu(s[src] + dh[0]) - mh[0]);
            ew[j] = w0;
            zh[0] += w0;
        }
    }
#pragma unroll
    for (int h = 0; h < H; ++h)
        for (int off = 32; off > 0; off >>= 1)
            zh[h] += __shfl_xor(zh[h], off);

    if (lane == 0) {
#pragma unroll
        for (int h = 0; h < H; ++h) {
            float ws = __expf(selfe[h] - mh[h]);
            wself[node * H + h] = ws;
            zinv[node * H + h] = 1.0f / (zh[h] + ws);
        }
    }
}

// ---------------------------------------------------------------------------
// SLICED gather: channel slice s (128 ch = 2.56 MB table slice, L2-resident)
// is pinned to XCD pair via id%8 heuristic (slice = (id&7)>>1). Block = 256
// thr = 4 waves, each wave one (node, slice). Within a wave: 4 edge
// subgroups x 16 lanes x 16 B (full 128-ch slice), combined via shfl.
// ---------------------------------------------------------------------------
__device__ __forceinline__ void acc8(float* acc, uint4 q, float w) {
    acc[0] += w * bf_lo(q.x); acc[1] += w * bf_hi(q.x);
    acc[2] += w * bf_lo(q.y); acc[3] += w * bf_hi(q.y);
    acc[4] += w * bf_lo(q.z); acc[5] += w * bf_hi(q.z);
    acc[6] += w * bf_lo(q.w); acc[7] += w * bf_hi(q.w);
}

template<int H>
__global__ __launch_bounds__(256) void gather_sliced_kernel(
    const uint4* __restrict__ xpb4,     // [node][64]
    const int* __restrict__ offsets, const int* __restrict__ esrc,
    const float* __restrict__ ew,       // [E][H]
    const float* __restrict__ wself,    // [node][H]
    const float* __restrict__ zinv,     // [node][H]
    const float* __restrict__ bias,     // [OUTC]
    float* __restrict__ out,            // [node][ldo]
    int OUTC, int ldo)
{
    int id = blockIdx.x;
    int xcd = id & 7;
    int slice = xcd >> 1;                       // 0..3 — pinned per XCD pair
    int sub2 = xcd & 1;
    int wv = threadIdx.x >> 6;
    int node = (id >> 3) * 8 + sub2 * 4 + wv;
    if (node >= NNODES) return;
    int lane = threadIdx.x & 63;
    int esub = lane >> 4;                       // edge subgroup 0..3
    int l16 = lane & 15;
    int h = (H == 4) ? slice : 0;
    int rowoff = slice * 16 + l16;              // uint4 index within 64-wide row

    float acc[8];
    if (esub == 0) {
        float ws = wself[node * H + h];
        uint4 p = xpb4[(size_t)node * 64 + rowoff];
        acc[0] = ws * bf_lo(p.x); acc[1] = ws * bf_hi(p.x);
        acc[2] = ws * bf_lo(p.y); acc[3] = ws * bf_hi(p.y);
        acc[4] = ws * bf_lo(p.z); acc[5] = ws * bf_hi(p.z);
        acc[6] = ws * bf_lo(p.w); acc[7] = ws * bf_hi(p.w);
    } else {
#pragma unroll
        for (int k = 0; k < 8; ++k) acc[k] = 0.f;
    }

    int e0 = offsets[node], e1 = offsets[node + 1];
    int j = e0 + esub;
    for (; j + 12 < e1; j += 16) {
        int s0 = esrc[j], s1 = esrc[j + 4], s2 = esrc[j + 8], s3 = esrc[j + 12];
        float w0 = ew[(size_t)j * H + h];
        float w1 = ew[(size_t)(j + 4) * H + h];
        float w2 = ew[(size_t)(j + 8) * H + h];
        float w3 = ew[(size_t)(j + 12) * H + h];
        uint4 q0 = xpb4[(size_t)s0 * 64 + rowoff];
        uint4 q1 = xpb4[(size_t)s1 * 64 + rowoff];
        uint4 q2 = xpb4[(size_t)s2 * 64 + rowoff];
        uint4 q3 = xpb4[(size_t)s3 * 64 + rowoff];
        acc8(acc, q0, w0);
        acc8(acc, q1, w1);
        acc8(acc, q2, w2);
        acc8(acc, q3, w3);
    }
    for (; j < e1; j += 4) {
        int s0 = esrc[j];
        float w0 = ew[(size_t)j * H + h];
        uint4 q0 = xpb4[(size_t)s0 * 64 + rowoff];
        acc8(acc, q0, w0);
    }

    // combine the 4 edge subgroups (lanes l16, l16+16, l16+32, l16+48)
#pragma unroll
    for (int k = 0; k < 8; ++k) {
        acc[k] += __shfl_xor(acc[k], 16);
        acc[k] += __shfl_xor(acc[k], 32);
    }

    if (esub == 0) {
        float zi = zinv[node * H + h];
        int cbase = slice * 128 + l16 * 8;
        size_t ob = (size_t)node * ldo + cbase;
        if (cbase + 7 < OUTC) {
            float4 o0 = make_float4(acc[0] * zi + bias[cbase + 0], acc[1] * zi + bias[cbase + 1],
                                    acc[2] * zi + bias[cbase + 2], acc[3] * zi + bias[cbase + 3]);
            float4 o1 = make_float4(acc[4] * zi + bias[cbase + 4], acc[5] * zi + bias[cbase + 5],
                                    acc[6] * zi + bias[cbase + 6], acc[7] * zi + bias[cbase + 7]);
            *(float4*)(out + ob) = o0;
            *(float4*)(out + ob + 4) = o1;
        } else {
#pragma unroll
            for (int k = 0; k < 8; ++k) {
                int c = cbase + k;
                if (c < OUTC) out[ob + k] = acc[k] * zi + bias[c];
            }
        }
    }
}

// ---------------------------------------------------------------------------
// BatchNorm: stats (64-block partials) -> tiny finalize -> wide apply+pack.
// ---------------------------------------------------------------------------
__global__ __launch_bounds__(512) void bn_stats_kernel(const float* __restrict__ h,
                                                       float* __restrict__ psum,
                                                       float* __restrict__ psumsq) {
    int c = threadIdx.x;  // 512
    int b = blockIdx.x;   // 64
    float sm = 0.f, sq = 0.f;
    for (int r = b; r < NNODES; r += 64) {
        float v = h[(size_t)r * 512 + c];
        sm += v;
        sq += v * v;
    }
    psum[b * 512 + c] = sm;
    psumsq[b * 512 + c] = sq;
}

__global__ __launch_bounds__(512) void bn_finalize_kernel(const float* __restrict__ psum,
                                                          const float* __restrict__ psumsq,
                                                          const float* __restrict__ gamma,
                                                          const float* __restrict__ beta,
                                                          float* __restrict__ scale,
                                                          float* __restrict__ shift) {
    int c = threadIdx.x;
    float sm = 0.f, sq = 0.f;
    for (int b = 0; b < 64; ++b) {
        sm += psum[b * 512 + c];
        sq += psumsq[b * 512 + c];
    }
    const float invN = 1.0f / (float)NNODES;
    float mu = sm * invN;
    float var = sq * invN - mu * mu;
    float sc = gamma[c] * rsqrtf(var + BN_EPS);
    scale[c] = sc;
    shift[c] = beta[c] - mu * sc;
}

__global__ __launch_bounds__(256) void bn_apply_kernel(const float* __restrict__ h,
                                                       const float* __restrict__ scale,
                                                       const float* __restrict__ shift,
                                                       uint_t* __restrict__ hbf) {
    int t = threadIdx.x, b = blockIdx.x;   // grid = 256
    int c0 = t * 2, c1 = c0 + 1;
    float sc0 = scale[c0], sc1 = scale[c1];
    float sh0 = shift[c0], sh1 = shift[c1];
    for (int r = b; r < NNODES; r += 256) {
        float2 hv = ((const float2*)(h + (size_t)r * 512))[t];
        float v0 = hv.x * sc0 + sh0;
        float v1 = hv.y * sc1 + sh1;
        v0 = (v0 > 0.f) ? v0 : (__expf(v0) - 1.0f);
        v1 = (v1 > 0.f) ? v1 : (__expf(v1) - 1.0f);
        hbf[r * 256 + t] = ((uint_t)f2bf(v1) << 16) | (uint_t)f2bf(v0);
    }
}

// ---------------------------------------------------------------------------
// launch — 24 dispatches
// ---------------------------------------------------------------------------
extern "C" void kernel_launch(void* const* d_in, const int* in_sizes, int n_in,
                              void* d_out, int out_size, void* d_ws, size_t ws_size,
                              hipStream_t stream) {
    const float* x      = (const float*)d_in[0];
    const int*   ei     = (const int*)d_in[1];
    const float* W1     = (const float*)d_in[2];
    const float* a_src1 = (const float*)d_in[3];
    const float* a_dst1 = (const float*)d_in[4];
    const float* b1     = (const float*)d_in[5];
    const float* g1     = (const float*)d_in[6];
    const float* be1    = (const float*)d_in[7];
    const float* W2     = (const float*)d_in[8];
    const float* a_src2 = (const float*)d_in[9];
    const float* a_dst2 = (const float*)d_in[10];
    const float* b2     = (const float*)d_in[11];
    const float* g2     = (const float*)d_in[12];
    const float* be2    = (const float*)d_in[13];
    const float* W3     = (const float*)d_in[14];
    const float* a_src3 = (const float*)d_in[15];
    const float* a_dst3 = (const float*)d_in[16];
    const float* b3     = (const float*)d_in[17];
    float* out = (float*)d_out;

    const int* e_src = ei;           // edge_index[0]
    const int* e_dst = ei + NEDGES;  // edge_index[1]

    // ---- workspace layout ----
    char* w = (char*)d_ws;
    ushort_t* x_bf = (ushort_t*)w;
    float*    hbuf = (float*)w;                               // alias after L1 GEMM
    float*    ew   = (float*)(w + (size_t)NNODES * HC_ * sizeof(float));  // tail 5.12 MB
    w += (size_t)NNODES * INF_ * sizeof(ushort_t);            // 25.6 MB
    uint_t* xpb = (uint_t*)w;  w += (size_t)NNODES * HC_ * sizeof(ushort_t);
    uint_t* hbf = (uint_t*)w;  w += (size_t)NNODES * HC_ * sizeof(ushort_t);
    ushort_t* Wt1 = (ushort_t*)w; w += (size_t)HC_ * INF_ * sizeof(ushort_t);
    ushort_t* Wt2 = (ushort_t*)w; w += (size_t)HC_ * HC_ * sizeof(ushort_t);
    ushort_t* Wt3 = (ushort_t*)w; w += (size_t)HC_ * HC_ * sizeof(ushort_t);
    int* counts  = (int*)w;    w += NNODES * sizeof(int);
    float* s_log = (float*)w;  w += NNODES * HEADS_ * sizeof(float);
    float* d_log = (float*)w;  w += NNODES * HEADS_ * sizeof(float);
    float* wself = (float*)w;  w += NNODES * HEADS_ * sizeof(float);
    float* zinv  = (float*)w;  w += NNODES * HEADS_ * sizeof(float);
    float* bnscale = (float*)w; w += HC_ * sizeof(float);
    float* bnshift = (float*)w; w += HC_ * sizeof(float);
    float* psum  = (float*)w;  w += 64 * HC_ * sizeof(float);
    float* psumsq= (float*)w;  w += 64 * HC_ * sizeof(float);
    int* offsets = (int*)w;    w += (NNODES + 1) * sizeof(int);
    int* cursor  = (int*)w;    w += NNODES * sizeof(int);
    int* esrc    = (int*)w;    w += NEDGES * sizeof(int);
    int* bsum    = (int*)w;    w += 64 * sizeof(int);

    dim3 gg(HC_ / 64, (NNODES + 63) / 64);           // (8, 157) plain 2-D grid
    const int lgGrid = (NNODES + 3) / 4;             // 2500 (logits / softmax)
    const int gaGrid = ((NNODES + 7) / 8) * 8;       // 10000 (sliced gather)
    const int scanBlocks = (NNODES + 255) / 256;     // 40

    zero_kernel<<<32, 256, 0, stream>>>((float*)counts, NNODES);
    count_kernel<<<(NEDGES + 255) / 256, 256, 0, stream>>>(e_dst, counts, NEDGES);
    scan1_kernel<<<scanBlocks, 256, 0, stream>>>(counts, offsets, bsum, NNODES);
    scan3b_kernel<<<scanBlocks, 256, 0, stream>>>(offsets, cursor, bsum, scanBlocks, NNODES);
    scatter_kernel<<<(NEDGES + 255) / 256, 256, 0, stream>>>(e_src, e_dst, cursor, esrc, NEDGES);
    {
        int TOT = CVX + CN1 + CN2 + CN3;
        convall_kernel<<<(TOT + 255) / 256, 256, 0, stream>>>(x, W1, W2, W3, x_bf, Wt1, Wt2, Wt3);
    }

    // ---- Layer 1 ----
    gemm_kernel<<<gg, 256, 0, stream>>>(x_bf, Wt1, (ushort_t*)xpb, NNODES, INF_);
    logits_kernel<HEADS_><<<lgGrid, 256, 0, stream>>>((const uint4*)xpb, a_src1, a_dst1, s_log, d_log, HC_);
    edge_softmax_kernel<HEADS_><<<lgGrid, 256, 0, stream>>>(s_log, d_log, offsets, esrc, ew, wself, zinv);
    gather_sliced_kernel<HEADS_><<<gaGrid, 256, 0, stream>>>((const uint4*)xpb, offsets, esrc,
        ew, wself, zinv, b1, hbuf, HC_, HC_);
    bn_stats_kernel<<<64, 512, 0, stream>>>(hbuf, psum, psumsq);
    bn_finalize_kernel<<<1, 512, 0, stream>>>(psum, psumsq, g1, be1, bnscale, bnshift);
    bn_apply_kernel<<<256, 256, 0, stream>>>(hbuf, bnscale, bnshift, hbf);

    // ---- Layer 2 ----
    gemm_kernel<<<gg, 256, 0, stream>>>((const ushort_t*)hbf, Wt2, (ushort_t*)xpb, NNODES, HC_);
    logits_kernel<HEADS_><<<lgGrid, 256, 0, stream>>>((const uint4*)xpb, a_src2, a_dst2, s_log, d_log, HC_);
    edge_softmax_kernel<HEADS_><<<lgGrid, 256, 0, stream>>>(s_log, d_log, offsets, esrc, ew, wself, zinv);
    gather_sliced_kernel<HEADS_><<<gaGrid, 256, 0, stream>>>((const uint4*)xpb, offsets, esrc,
        ew, wself, zinv, b2, hbuf, HC_, HC_);
    bn_stats_kernel<<<64, 512, 0, stream>>>(hbuf, psum, psumsq);
    bn_finalize_kernel<<<1, 512, 0, stream>>>(psum, psumsq, g2, be2, bnscale, bnshift);
    bn_apply_kernel<<<256, 256, 0, stream>>>(hbuf, bnscale, bnshift, hbf);

    // ---- Layer 3 (H=1, N=500) ----
    gemm_kernel<<<gg, 256, 0, stream>>>((const ushort_t*)hbf, Wt3, (ushort_t*)xpb, NNODES, HC_);
    logits_kernel<1><<<lgGrid, 256, 0, stream>>>((const uint4*)xpb, a_src3, a_dst3, s_log, d_log, OUTF_);
    edge_softmax_kernel<1><<<lgGrid, 256, 0, stream>>>(s_log, d_log, offsets, esrc, ew, wself, zinv);
    gather_sliced_kernel<1><<<gaGrid, 256, 0, stream>>>((const uint4*)xpb, offsets, esrc,
        ew, wself, zinv, b3, out, OUTF_, OUTF_);
}

// Round 14
// 492.970 us; speedup vs baseline: 1.0646x; 1.0126x over previous
//
#include <hip/hip_runtime.h>
#include <hip/hip_bf16.h>

// Problem constants (from reference)
#define NNODES 10000
#define NEDGES 320000
#define INF_   1280
#define HID_   128
#define HEADS_ 4
#define OUTF_  500
#define HC_    512          // HEADS_*HID_
#define NEG_SLOPE 0.2f
#define BN_EPS 1e-5f

typedef __attribute__((ext_vector_type(8))) short short8x;
typedef __attribute__((ext_vector_type(4))) float f32x4;
typedef unsigned short ushort_t;
typedef unsigned int uint_t;

__device__ __forceinline__ ushort_t f2bf(float f) {
    uint_t u = __float_as_uint(f);
    u = (u + 0x7fffu + ((u >> 16) & 1u)) >> 16;   // round-to-nearest-even
    return (ushort_t)u;
}
__device__ __forceinline__ float bf_lo(uint_t p) { return __uint_as_float(p << 16); }
__device__ __forceinline__ float bf_hi(uint_t p) { return __uint_as_float(p & 0xffff0000u); }
__device__ __forceinline__ float lrelu(float x) { return (x >= 0.f) ? x : NEG_SLOPE * x; }
__device__ __forceinline__ uint_t pack_bf16_rn(float a, float b) {
    __hip_bfloat162 h = __float22bfloat162_rn(make_float2(a, b));  // hw packed cvt, RNE
    return *(uint_t*)&h;
}

// ---------------------------------------------------------------------------
// utility
// ---------------------------------------------------------------------------
__global__ void zero_kernel(float* __restrict__ p, size_t n) {
    size_t i = (size_t)blockIdx.x * blockDim.x + threadIdx.x;
    size_t stride = (size_t)gridDim.x * blockDim.x;
    for (; i < n; i += stride) p[i] = 0.0f;
}

// one kernel: x->bf16 (vectorized) + 3 weight transposes
#define CVX (NNODES * INF_ / 4)        // 3,200,000 float4 chunks of x
#define CN1 (HC_ * INF_)
#define CN2 (HC_ * HC_)
#define CN3 (HC_ * HC_)                // Wt3 (padded rows)
__global__ void convall_kernel(const float* __restrict__ x,
                               const float* __restrict__ W1,
                               const float* __restrict__ W2,
                               const float* __restrict__ W3,
                               ushort_t* __restrict__ x_bf,
                               ushort_t* __restrict__ Wt1,
                               ushort_t* __restrict__ Wt2,
                               ushort_t* __restrict__ Wt3) {
    int i = blockIdx.x * blockDim.x + threadIdx.x;
    if (i < CVX) {
        float4 v = ((const float4*)x)[i];
        ((uint2*)x_bf)[i] = make_uint2(pack_bf16_rn(v.x, v.y), pack_bf16_rn(v.z, v.w));
    } else if (i < CVX + CN1) {
        int j = i - CVX;
        int n = j / INF_, k = j - n * INF_;
        Wt1[j] = f2bf(W1[(size_t)k * HC_ + n]);
    } else if (i < CVX + CN1 + CN2) {
        int j = i - CVX - CN1;
        int n = j / HC_, k = j - n * HC_;
        Wt2[j] = f2bf(W2[(size_t)k * HC_ + n]);
    } else if (i < CVX + CN1 + CN2 + CN3) {
        int j = i - CVX - CN1 - CN2;
        int n = j / HC_, k = j - n * HC_;
        Wt3[j] = (n < OUTF_) ? f2bf(W3[(size_t)k * OUTF_ + n]) : (ushort_t)0;
    }
}

// ---------------------------------------------------------------------------
// CSR build (by destination)
// ---------------------------------------------------------------------------
__global__ void count_kernel(const int* __restrict__ dst, int* __restrict__ counts, int E) {
    int e = blockIdx.x * blockDim.x + threadIdx.x;
    if (e < E) atomicAdd(&counts[dst[e]], 1);
}

__global__ __launch_bounds__(256) void scan1_kernel(const int* __restrict__ counts,
                                                    int* __restrict__ offsets,
                                                    int* __restrict__ bsum, int n) {
    __shared__ int tmp[256];
    int b = blockIdx.x, t = threadIdx.x;
    int i = b * 256 + t;
    int v = (i < n) ? counts[i] : 0;
    tmp[t] = v;
    __syncthreads();
    for (int off = 1; off < 256; off <<= 1) {
        int u = (t >= off) ? tmp[t - off] : 0;
        __syncthreads();
        tmp[t] += u;
        __syncthreads();
    }
    if (i < n) offsets[i] = tmp[t] - v;
    if (t == 255) bsum[b] = tmp[t];
}

__global__ __launch_bounds__(256) void scan3b_kernel(int* __restrict__ offsets,
                                                     int* __restrict__ cursor,
                                                     const int* __restrict__ bsum,
                                                     int nb, int n) {
    __shared__ int base_sh, tot_sh;
    int b = blockIdx.x, t = threadIdx.x;
    if (t == 0) {
        int acc = 0, tot = 0;
        for (int k = 0; k < nb; ++k) { if (k < b) acc += bsum[k]; tot += bsum[k]; }
        base_sh = acc; tot_sh = tot;
    }
    __syncthreads();
    int i = b * 256 + t;
    if (i < n) {
        int v = offsets[i] + base_sh;
        offsets[i] = v;
        cursor[i] = v;
    }
    if (b == nb - 1 && t == 0) offsets[n] = tot_sh;
}

__global__ void scatter_kernel(const int* __restrict__ src, const int* __restrict__ dst,
                               int* __restrict__ cursor, int* __restrict__ esrc, int E) {
    int e = blockIdx.x * blockDim.x + threadIdx.x;
    if (e < E) {
        int p = atomicAdd(&cursor[dst[e]], 1);
        esrc[p] = src[e];
    }
}

// ---------------------------------------------------------------------------
// bf16 MFMA GEMM — 64(M) x 128(N) tile, BK=32, plain 2-D grid.
//   Halves A-replication vs 64x64 (4 col-blocks instead of 8 for N=512):
//   logical A traffic 205->102 MB. 4 waves in 2x2: wave = 32x64 sub-tile
//   (2x4 MFMAs/K-step). Grid (4, 157) = 628 blocks.
// ---------------------------------------------------------------------------
#define LDT 40

__global__ __launch_bounds__(256) void gemm_kernel(
    const ushort_t* __restrict__ A,    // [M][K] bf16
    const ushort_t* __restrict__ Bt,   // [512][K] bf16 (transposed, padded)
    ushort_t* __restrict__ Cb,         // [M][512] bf16
    int M, int K)
{
    __shared__ __align__(16) ushort_t As[64 * LDT];
    __shared__ __align__(16) ushort_t Bs[128 * LDT];

    int m0 = blockIdx.y * 64;
    int n0 = blockIdx.x * 128;

    int tid  = threadIdx.x;
    int lane = tid & 63;
    int w    = tid >> 6;
    int wm   = (w & 1) * 32;       // wave m-offset
    int wn   = (w >> 1) * 64;      // wave n-offset
    int quad = lane >> 4;
    int c16  = lane & 15;

    f32x4 acc[2][4];
#pragma unroll
    for (int i = 0; i < 2; ++i)
#pragma unroll
        for (int j = 0; j < 4; ++j)
#pragma unroll
            for (int r = 0; r < 4; ++r) acc[i][j][r] = 0.0f;

    int sr = tid >> 2;          // A: 0..63 row, k chunk 0..3
    int sk = (tid & 3) * 8;

    for (int k0 = 0; k0 < K; k0 += 32) {
        int gm = m0 + sr;
        if (gm > M - 1) gm = M - 1;
        uint4 av = *(const uint4*)(A + (size_t)gm * K + k0 + sk);
        *(uint4*)&As[sr * LDT + sk] = av;

        // B tile 128 rows x 32 k = 512 uint4 chunks -> 2 per thread
#pragma unroll
        for (int t = 0; t < 2; ++t) {
            int ci = t * 256 + tid;
            int row = ci >> 2;
            int kc = (ci & 3) * 8;
            uint4 bv = *(const uint4*)(Bt + (size_t)(n0 + row) * K + k0 + kc);
            *(uint4*)&Bs[row * LDT + kc] = bv;
        }
        __syncthreads();

        short8x af0 = *(const short8x*)&As[(wm +      c16) * LDT + quad * 8];
        short8x af1 = *(const short8x*)&As[(wm + 16 + c16) * LDT + quad * 8];
        short8x bf[4];
#pragma unroll
        for (int nt = 0; nt < 4; ++nt)
            bf[nt] = *(const short8x*)&Bs[(wn + nt * 16 + c16) * LDT + quad * 8];

#pragma unroll
        for (int nt = 0; nt < 4; ++nt) {
            acc[0][nt] = __builtin_amdgcn_mfma_f32_16x16x32_bf16(af0, bf[nt], acc[0][nt], 0, 0, 0);
            acc[1][nt] = __builtin_amdgcn_mfma_f32_16x16x32_bf16(af1, bf[nt], acc[1][nt], 0, 0, 0);
        }
        __syncthreads();
    }

#pragma unroll
    for (int mt = 0; mt < 2; ++mt) {
#pragma unroll
        for (int r = 0; r < 4; ++r) {
            int row = m0 + wm + mt * 16 + quad * 4 + r;
            if (row < M) {
#pragma unroll
                for (int nt = 0; nt < 4; ++nt) {
                    int col = n0 + wn + nt * 16 + c16;
                    Cb[(size_t)row * 512 + col] = f2bf(acc[mt][nt][r]);
                }
            }
        }
    }
}

// ---------------------------------------------------------------------------
// logits: one wave per node (4 nodes/block). Lane l owns channels [8l, 8l+8).
// ---------------------------------------------------------------------------
template<int H>
__global__ __launch_bounds__(256) void logits_kernel(
    const uint4* __restrict__ xpb4,    // [node][64]
    const float* __restrict__ aS, const float* __restrict__ aD,
    float* __restrict__ s_log, float* __restrict__ d_log, int OUTC)
{
    int node = blockIdx.x * 4 + (threadIdx.x >> 6);
    if (node >= NNODES) return;
    int lane = threadIdx.x & 63;
    uint4 p = xpb4[(size_t)node * 64 + lane];
    float xv[8] = {bf_lo(p.x), bf_hi(p.x), bf_lo(p.y), bf_hi(p.y),
                   bf_lo(p.z), bf_hi(p.z), bf_lo(p.w), bf_hi(p.w)};
    int cbase = lane * 8;
    float sv = 0.f, dv = 0.f;
    if (cbase + 7 < OUTC) {
        float4 a0 = ((const float4*)aS)[lane * 2];
        float4 a1 = ((const float4*)aS)[lane * 2 + 1];
        float4 b0 = ((const float4*)aD)[lane * 2];
        float4 b1 = ((const float4*)aD)[lane * 2 + 1];
        sv = xv[0]*a0.x + xv[1]*a0.y + xv[2]*a0.z + xv[3]*a0.w
           + xv[4]*a1.x + xv[5]*a1.y + xv[6]*a1.z + xv[7]*a1.w;
        dv = xv[0]*b0.x + xv[1]*b0.y + xv[2]*b0.z + xv[3]*b0.w
           + xv[4]*b1.x + xv[5]*b1.y + xv[6]*b1.z + xv[7]*b1.w;
    } else {
#pragma unroll
        for (int k = 0; k < 8; ++k) {
            int c = cbase + k;
            if (c < OUTC) { sv += xv[k] * aS[c]; dv += xv[k] * aD[c]; }
        }
    }
    int grp = (H == 4) ? 16 : 64;
    for (int off = 1; off < grp; off <<= 1) {
        sv += __shfl_xor(sv, off);
        dv += __shfl_xor(dv, off);
    }
    if ((lane & (grp - 1)) == 0) {
        int h = (H == 4) ? (lane >> 4) : 0;
        s_log[node * H + h] = sv;
        d_log[node * H + h] = dv;
    }
}

// ---------------------------------------------------------------------------
// edge softmax (wave-per-node, 4 nodes/block): writes ew + wself + zinv.
// ---------------------------------------------------------------------------
template<int H>
__global__ __launch_bounds__(256) void edge_softmax_kernel(
    const float* __restrict__ s, const float* __restrict__ dlog,
    const int* __restrict__ offsets, const int* __restrict__ esrc,
    float* __restrict__ ew, float* __restrict__ wself, float* __restrict__ zinv)
{
    int node = blockIdx.x * 4 + (threadIdx.x >> 6);
    if (node >= NNODES) return;
    int lane = threadIdx.x & 63;
    int e0 = offsets[node], e1 = offsets[node + 1];

    float dh[H], selfe[H], mh[H], zh[H];
#pragma unroll
    for (int h = 0; h < H; ++h) {
        dh[h] = dlog[node * H + h];
        selfe[h] = lrelu(s[node * H + h] + dh[h]);
        mh[h] = selfe[h];
        zh[h] = 0.f;
    }
    for (int j = e0 + lane; j < e1; j += 64) {
        int src = esrc[j];
        if (H == 4) {
            float4 sv = ((const float4*)s)[src];
            mh[0] = fmaxf(mh[0], lrelu(sv.x + dh[0]));
            mh[1] = fmaxf(mh[1], lrelu(sv.y + dh[1]));
            mh[2] = fmaxf(mh[2], lrelu(sv.z + dh[2]));
            mh[3] = fmaxf(mh[3], lrelu(sv.w + dh[3]));
        } else {
            mh[0] = fmaxf(mh[0], lrelu(s[src] + dh[0]));
        }
    }
#pragma unroll
    for (int h = 0; h < H; ++h)
        for (int off = 32; off > 0; off >>= 1)
            mh[h] = fmaxf(mh[h], __shfl_xor(mh[h], off));

    for (int j = e0 + lane; j < e1; j += 64) {
        int src = esrc[j];
        if (H == 4) {
            float4 sv = ((const float4*)s)[src];
            float w0 = __expf(lrelu(sv.x + dh[0]) - mh[0]);
            float w1 = __expf(lrelu(sv.y + dh[1]) - mh[1]);
            float w2 = __expf(lrelu(sv.z + dh[2]) - mh[2]);
            float w3 = __expf(lrelu(sv.w + dh[3]) - mh[3]);
            ((float4*)ew)[j] = make_float4(w0, w1, w2, w3);
            zh[0] += w0; zh[1] += w1; zh[2] += w2; zh[3] += w3;
        } else {
            float w0 = __expf(lrelu(s[src] + dh[0]) - mh[0]);
            ew[j] = w0;
            zh[0] += w0;
        }
    }
#pragma unroll
    for (int h = 0; h < H; ++h)
        for (int off = 32; off > 0; off >>= 1)
            zh[h] += __shfl_xor(zh[h], off);

    if (lane == 0) {
#pragma unroll
        for (int h = 0; h < H; ++h) {
            float ws = __expf(selfe[h] - mh[h]);
            wself[node * H + h] = ws;
            zinv[node * H + h] = 1.0f / (zh[h] + ws);
        }
    }
}

// ---------------------------------------------------------------------------
// SLICED gather (R13, proven): slice pinned per XCD pair, 2.56 MB L2-resident.
// ---------------------------------------------------------------------------
__device__ __forceinline__ void acc8(float* acc, uint4 q, float w) {
    acc[0] += w * bf_lo(q.x); acc[1] += w * bf_hi(q.x);
    acc[2] += w * bf_lo(q.y); acc[3] += w * bf_hi(q.y);
    acc[4] += w * bf_lo(q.z); acc[5] += w * bf_hi(q.z);
    acc[6] += w * bf_lo(q.w); acc[7] += w * bf_hi(q.w);
}

template<int H>
__global__ __launch_bounds__(256) void gather_sliced_kernel(
    const uint4* __restrict__ xpb4,     // [node][64]
    const int* __restrict__ offsets, const int* __restrict__ esrc,
    const float* __restrict__ ew,       // [E][H]
    const float* __restrict__ wself,    // [node][H]
    const float* __restrict__ zinv,     // [node][H]
    const float* __restrict__ bias,     // [OUTC]
    float* __restrict__ out,            // [node][ldo]
    int OUTC, int ldo)
{
    int id = blockIdx.x;
    int xcd = id & 7;
    int slice = xcd >> 1;                       // 0..3 — pinned per XCD pair
    int sub2 = xcd & 1;
    int wv = threadIdx.x >> 6;
    int node = (id >> 3) * 8 + sub2 * 4 + wv;
    if (node >= NNODES) return;
    int lane = threadIdx.x & 63;
    int esub = lane >> 4;                       // edge subgroup 0..3
    int l16 = lane & 15;
    int h = (H == 4) ? slice : 0;
    int rowoff = slice * 16 + l16;              // uint4 index within 64-wide row

    float acc[8];
    if (esub == 0) {
        float ws = wself[node * H + h];
        uint4 p = xpb4[(size_t)node * 64 + rowoff];
        acc[0] = ws * bf_lo(p.x); acc[1] = ws * bf_hi(p.x);
        acc[2] = ws * bf_lo(p.y); acc[3] = ws * bf_hi(p.y);
        acc[4] = ws * bf_lo(p.z); acc[5] = ws * bf_hi(p.z);
        acc[6] = ws * bf_lo(p.w); acc[7] = ws * bf_hi(p.w);
    } else {
#pragma unroll
        for (int k = 0; k < 8; ++k) acc[k] = 0.f;
    }

    int e0 = offsets[node], e1 = offsets[node + 1];
    int j = e0 + esub;
    for (; j + 12 < e1; j += 16) {
        int s0 = esrc[j], s1 = esrc[j + 4], s2 = esrc[j + 8], s3 = esrc[j + 12];
        float w0 = ew[(size_t)j * H + h];
        float w1 = ew[(size_t)(j + 4) * H + h];
        float w2 = ew[(size_t)(j + 8) * H + h];
        float w3 = ew[(size_t)(j + 12) * H + h];
        uint4 q0 = xpb4[(size_t)s0 * 64 + rowoff];
        uint4 q1 = xpb4[(size_t)s1 * 64 + rowoff];
        uint4 q2 = xpb4[(size_t)s2 * 64 + rowoff];
        uint4 q3 = xpb4[(size_t)s3 * 64 + rowoff];
        acc8(acc, q0, w0);
        acc8(acc, q1, w1);
        acc8(acc, q2, w2);
        acc8(acc, q3, w3);
    }
    for (; j < e1; j += 4) {
        int s0 = esrc[j];
        float w0 = ew[(size_t)j * H + h];
        uint4 q0 = xpb4[(size_t)s0 * 64 + rowoff];
        acc8(acc, q0, w0);
    }

    // combine the 4 edge subgroups
#pragma unroll
    for (int k = 0; k < 8; ++k) {
        acc[k] += __shfl_xor(acc[k], 16);
        acc[k] += __shfl_xor(acc[k], 32);
    }

    if (esub == 0) {
        float zi = zinv[node * H + h];
        int cbase = slice * 128 + l16 * 8;
        size_t ob = (size_t)node * ldo + cbase;
        if (cbase + 7 < OUTC) {
            float4 o0 = make_float4(acc[0] * zi + bias[cbase + 0], acc[1] * zi + bias[cbase + 1],
                                    acc[2] * zi + bias[cbase + 2], acc[3] * zi + bias[cbase + 3]);
            float4 o1 = make_float4(acc[4] * zi + bias[cbase + 4], acc[5] * zi + bias[cbase + 5],
                                    acc[6] * zi + bias[cbase + 6], acc[7] * zi + bias[cbase + 7]);
            *(float4*)(out + ob) = o0;
            *(float4*)(out + ob + 4) = o1;
        } else {
#pragma unroll
            for (int k = 0; k < 8; ++k) {
                int c = cbase + k;
                if (c < OUTC) out[ob + k] = acc[k] * zi + bias[c];
            }
        }
    }
}

// ---------------------------------------------------------------------------
// BatchNorm: stats (64-block partials) -> tiny finalize -> wide apply+pack.
// ---------------------------------------------------------------------------
__global__ __launch_bounds__(512) void bn_stats_kernel(const float* __restrict__ h,
                                                       float* __restrict__ psum,
                                                       float* __restrict__ psumsq) {
    int c = threadIdx.x;  // 512
    int b = blockIdx.x;   // 64
    float sm = 0.f, sq = 0.f;
    for (int r = b; r < NNODES; r += 64) {
        float v = h[(size_t)r * 512 + c];
        sm += v;
        sq += v * v;
    }
    psum[b * 512 + c] = sm;
    psumsq[b * 512 + c] = sq;
}

__global__ __launch_bounds__(512) void bn_finalize_kernel(const float* __restrict__ psum,
                                                          const float* __restrict__ psumsq,
                                                          const float* __restrict__ gamma,
                                                          const float* __restrict__ beta,
                                                          float* __restrict__ scale,
                                                          float* __restrict__ shift) {
    int c = threadIdx.x;
    float sm = 0.f, sq = 0.f;
    for (int b = 0; b < 64; ++b) {
        sm += psum[b * 512 + c];
        sq += psumsq[b * 512 + c];
    }
    const float invN = 1.0f / (float)NNODES;
    float mu = sm * invN;
    float var = sq * invN - mu * mu;
    float sc = gamma[c] * rsqrtf(var + BN_EPS);
    scale[c] = sc;
    shift[c] = beta[c] - mu * sc;
}

__global__ __launch_bounds__(256) void bn_apply_kernel(const float* __restrict__ h,
                                                       const float* __restrict__ scale,
                                                       const float* __restrict__ shift,
                                                       uint_t* __restrict__ hbf) {
    int t = threadIdx.x, b = blockIdx.x;   // grid = 256
    int c0 = t * 2, c1 = c0 + 1;
    float sc0 = scale[c0], sc1 = scale[c1];
    float sh0 = shift[c0], sh1 = shift[c1];
    for (int r = b; r < NNODES; r += 256) {
        float2 hv = ((const float2*)(h + (size_t)r * 512))[t];
        float v0 = hv.x * sc0 + sh0;
        float v1 = hv.y * sc1 + sh1;
        v0 = (v0 > 0.f) ? v0 : (__expf(v0) - 1.0f);
        v1 = (v1 > 0.f) ? v1 : (__expf(v1) - 1.0f);
        hbf[r * 256 + t] = ((uint_t)f2bf(v1) << 16) | (uint_t)f2bf(v0);
    }
}

// ---------------------------------------------------------------------------
// launch — 24 dispatches
// ---------------------------------------------------------------------------
extern "C" void kernel_launch(void* const* d_in, const int* in_sizes, int n_in,
                              void* d_out, int out_size, void* d_ws, size_t ws_size,
                              hipStream_t stream) {
    const float* x      = (const float*)d_in[0];
    const int*   ei     = (const int*)d_in[1];
    const float* W1     = (const float*)d_in[2];
    const float* a_src1 = (const float*)d_in[3];
    const float* a_dst1 = (const float*)d_in[4];
    const float* b1     = (const float*)d_in[5];
    const float* g1     = (const float*)d_in[6];
    const float* be1    = (const float*)d_in[7];
    const float* W2     = (const float*)d_in[8];
    const float* a_src2 = (const float*)d_in[9];
    const float* a_dst2 = (const float*)d_in[10];
    const float* b2     = (const float*)d_in[11];
    const float* g2     = (const float*)d_in[12];
    const float* be2    = (const float*)d_in[13];
    const float* W3     = (const float*)d_in[14];
    const float* a_src3 = (const float*)d_in[15];
    const float* a_dst3 = (const float*)d_in[16];
    const float* b3     = (const float*)d_in[17];
    float* out = (float*)d_out;

    const int* e_src = ei;           // edge_index[0]
    const int* e_dst = ei + NEDGES;  // edge_index[1]

    // ---- workspace layout ----
    char* w = (char*)d_ws;
    ushort_t* x_bf = (ushort_t*)w;
    float*    hbuf = (float*)w;                               // alias after L1 GEMM
    float*    ew   = (float*)(w + (size_t)NNODES * HC_ * sizeof(float));  // tail 5.12 MB
    w += (size_t)NNODES * INF_ * sizeof(ushort_t);            // 25.6 MB
    uint_t* xpb = (uint_t*)w;  w += (size_t)NNODES * HC_ * sizeof(ushort_t);
    uint_t* hbf = (uint_t*)w;  w += (size_t)NNODES * HC_ * sizeof(ushort_t);
    ushort_t* Wt1 = (ushort_t*)w; w += (size_t)HC_ * INF_ * sizeof(ushort_t);
    ushort_t* Wt2 = (ushort_t*)w; w += (size_t)HC_ * HC_ * sizeof(ushort_t);
    ushort_t* Wt3 = (ushort_t*)w; w += (size_t)HC_ * HC_ * sizeof(ushort_t);
    int* counts  = (int*)w;    w += NNODES * sizeof(int);
    float* s_log = (float*)w;  w += NNODES * HEADS_ * sizeof(float);
    float* d_log = (float*)w;  w += NNODES * HEADS_ * sizeof(float);
    float* wself = (float*)w;  w += NNODES * HEADS_ * sizeof(float);
    float* zinv  = (float*)w;  w += NNODES * HEADS_ * sizeof(float);
    float* bnscale = (float*)w; w += HC_ * sizeof(float);
    float* bnshift = (float*)w; w += HC_ * sizeof(float);
    float* psum  = (float*)w;  w += 64 * HC_ * sizeof(float);
    float* psumsq= (float*)w;  w += 64 * HC_ * sizeof(float);
    int* offsets = (int*)w;    w += (NNODES + 1) * sizeof(int);
    int* cursor  = (int*)w;    w += NNODES * sizeof(int);
    int* esrc    = (int*)w;    w += NEDGES * sizeof(int);
    int* bsum    = (int*)w;    w += 64 * sizeof(int);

    dim3 gg(HC_ / 128, (NNODES + 63) / 64);          // (4, 157) — 64x128 tile
    const int lgGrid = (NNODES + 3) / 4;             // 2500 (logits / softmax)
    const int gaGrid = ((NNODES + 7) / 8) * 8;       // 10000 (sliced gather)
    const int scanBlocks = (NNODES + 255) / 256;     // 40

    zero_kernel<<<32, 256, 0, stream>>>((float*)counts, NNODES);
    count_kernel<<<(NEDGES + 255) / 256, 256, 0, stream>>>(e_dst, counts, NEDGES);
    scan1_kernel<<<scanBlocks, 256, 0, stream>>>(counts, offsets, bsum, NNODES);
    scan3b_kernel<<<scanBlocks, 256, 0, stream>>>(offsets, cursor, bsum, scanBlocks, NNODES);
    scatter_kernel<<<(NEDGES + 255) / 256, 256, 0, stream>>>(e_src, e_dst, cursor, esrc, NEDGES);
    {
        int TOT = CVX + CN1 + CN2 + CN3;
        convall_kernel<<<(TOT + 255) / 256, 256, 0, stream>>>(x, W1, W2, W3, x_bf, Wt1, Wt2, Wt3);
    }

    // ---- Layer 1 ----
    gemm_kernel<<<gg, 256, 0, stream>>>(x_bf, Wt1, (ushort_t*)xpb, NNODES, INF_);
    logits_kernel<HEADS_><<<lgGrid, 256, 0, stream>>>((const uint4*)xpb, a_src1, a_dst1, s_log, d_log, HC_);
    edge_softmax_kernel<HEADS_><<<lgGrid, 256, 0, stream>>>(s_log, d_log, offsets, esrc, ew, wself, zinv);
    gather_sliced_kernel<HEADS_><<<gaGrid, 256, 0, stream>>>((const uint4*)xpb, offsets, esrc,
        ew, wself, zinv, b1, hbuf, HC_, HC_);
    bn_stats_kernel<<<64, 512, 0, stream>>>(hbuf, psum, psumsq);
    bn_finalize_kernel<<<1, 512, 0, stream>>>(psum, psumsq, g1, be1, bnscale, bnshift);
    bn_apply_kernel<<<256, 256, 0, stream>>>(hbuf, bnscale, bnshift, hbf);

    // ---- Layer 2 ----
    gemm_kernel<<<gg, 256, 0, stream>>>((const ushort_t*)hbf, Wt2, (ushort_t*)xpb, NNODES, HC_);
    logits_kernel<HEADS_><<<lgGrid, 256, 0, stream>>>((const uint4*)xpb, a_src2, a_dst2, s_log, d_log, HC_);
    edge_softmax_kernel<HEADS_><<<lgGrid, 256, 0, stream>>>(s_log, d_log, offsets, esrc, ew, wself, zinv);
    gather_sliced_kernel<HEADS_><<<gaGrid, 256, 0, stream>>>((const uint4*)xpb, offsets, esrc,
        ew, wself, zinv, b2, hbuf, HC_, HC_);
    bn_stats_kernel<<<64, 512, 0, stream>>>(hbuf, psum, psumsq);
    bn_finalize_kernel<<<1, 512, 0, stream>>>(psum, psumsq, g2, be2, bnscale, bnshift);
    bn_apply_kernel<<<256, 256, 0, stream>>>(hbuf, bnscale, bnshift, hbf);

    // ---- Layer 3 (H=1, N=500) ----
    gemm_kernel<<<gg, 256, 0, stream>>>((const ushort_t*)hbf, Wt3, (ushort_t*)xpb, NNODES, HC_);
    logits_kernel<1><<<lgGrid, 256, 0, stream>>>((const uint4*)xpb, a_src3, a_dst3, s_log, d_log, OUTF_);
    edge_softmax_kernel<1><<<lgGrid, 256, 0, stream>>>(s_log, d_log, offsets, esrc, ew, wself, zinv);
    gather_sliced_kernel<1><<<gaGrid, 256, 0, stream>>>((const uint4*)xpb, offsets, esrc,
        ew, wself, zinv, b3, out, OUTF_, OUTF_);
}

// Round 15
// 486.602 us; speedup vs baseline: 1.0785x; 1.0131x over previous
//
#include <hip/hip_runtime.h>
#include <hip/hip_bf16.h>

// Problem constants (from reference)
#define NNODES 10000
#define NEDGES 320000
#define INF_   1280
#define HID_   128
#define HEADS_ 4
#define OUTF_  500
#define HC_    512          // HEADS_*HID_
#define NEG_SLOPE 0.2f
#define BN_EPS 1e-5f

typedef __attribute__((ext_vector_type(8))) short short8x;
typedef __attribute__((ext_vector_type(4))) float f32x4;
typedef unsigned short ushort_t;
typedef unsigned int uint_t;

__device__ __forceinline__ ushort_t f2bf(float f) {
    uint_t u = __float_as_uint(f);
    u = (u + 0x7fffu + ((u >> 16) & 1u)) >> 16;   // round-to-nearest-even
    return (ushort_t)u;
}
__device__ __forceinline__ float bf_lo(uint_t p) { return __uint_as_float(p << 16); }
__device__ __forceinline__ float bf_hi(uint_t p) { return __uint_as_float(p & 0xffff0000u); }
__device__ __forceinline__ float lrelu(float x) { return (x >= 0.f) ? x : NEG_SLOPE * x; }
__device__ __forceinline__ uint_t pack_bf16_rn(float a, float b) {
    __hip_bfloat162 h = __float22bfloat162_rn(make_float2(a, b));  // hw packed cvt, RNE
    return *(uint_t*)&h;
}

// ---------------------------------------------------------------------------
// utility
// ---------------------------------------------------------------------------
__global__ void zero_kernel(float* __restrict__ p, size_t n) {
    size_t i = (size_t)blockIdx.x * blockDim.x + threadIdx.x;
    size_t stride = (size_t)gridDim.x * blockDim.x;
    for (; i < n; i += stride) p[i] = 0.0f;
}

// one kernel: x->bf16 (vectorized) + 3 weight transposes
#define CVX (NNODES * INF_ / 4)        // 3,200,000 float4 chunks of x
#define CN1 (HC_ * INF_)
#define CN2 (HC_ * HC_)
#define CN3 (HC_ * HC_)                // Wt3 (padded rows)
__global__ void convall_kernel(const float* __restrict__ x,
                               const float* __restrict__ W1,
                               const float* __restrict__ W2,
                               const float* __restrict__ W3,
                               ushort_t* __restrict__ x_bf,
                               ushort_t* __restrict__ Wt1,
                               ushort_t* __restrict__ Wt2,
                               ushort_t* __restrict__ Wt3) {
    int i = blockIdx.x * blockDim.x + threadIdx.x;
    if (i < CVX) {
        float4 v = ((const float4*)x)[i];
        ((uint2*)x_bf)[i] = make_uint2(pack_bf16_rn(v.x, v.y), pack_bf16_rn(v.z, v.w));
    } else if (i < CVX + CN1) {
        int j = i - CVX;
        int n = j / INF_, k = j - n * INF_;
        Wt1[j] = f2bf(W1[(size_t)k * HC_ + n]);
    } else if (i < CVX + CN1 + CN2) {
        int j = i - CVX - CN1;
        int n = j / HC_, k = j - n * HC_;
        Wt2[j] = f2bf(W2[(size_t)k * HC_ + n]);
    } else if (i < CVX + CN1 + CN2 + CN3) {
        int j = i - CVX - CN1 - CN2;
        int n = j / HC_, k = j - n * HC_;
        Wt3[j] = (n < OUTF_) ? f2bf(W3[(size_t)k * OUTF_ + n]) : (ushort_t)0;
    }
}

// ---------------------------------------------------------------------------
// CSR build (by destination)
// ---------------------------------------------------------------------------
__global__ void count_kernel(const int* __restrict__ dst, int* __restrict__ counts, int E) {
    int e = blockIdx.x * blockDim.x + threadIdx.x;
    if (e < E) atomicAdd(&counts[dst[e]], 1);
}

__global__ __launch_bounds__(256) void scan1_kernel(const int* __restrict__ counts,
                                                    int* __restrict__ offsets,
                                                    int* __restrict__ bsum, int n) {
    __shared__ int tmp[256];
    int b = blockIdx.x, t = threadIdx.x;
    int i = b * 256 + t;
    int v = (i < n) ? counts[i] : 0;
    tmp[t] = v;
    __syncthreads();
    for (int off = 1; off < 256; off <<= 1) {
        int u = (t >= off) ? tmp[t - off] : 0;
        __syncthreads();
        tmp[t] += u;
        __syncthreads();
    }
    if (i < n) offsets[i] = tmp[t] - v;
    if (t == 255) bsum[b] = tmp[t];
}

__global__ __launch_bounds__(256) void scan3b_kernel(int* __restrict__ offsets,
                                                     int* __restrict__ cursor,
                                                     const int* __restrict__ bsum,
                                                     int nb, int n) {
    __shared__ int base_sh, tot_sh;
    int b = blockIdx.x, t = threadIdx.x;
    if (t == 0) {
        int acc = 0, tot = 0;
        for (int k = 0; k < nb; ++k) { if (k < b) acc += bsum[k]; tot += bsum[k]; }
        base_sh = acc; tot_sh = tot;
    }
    __syncthreads();
    int i = b * 256 + t;
    if (i < n) {
        int v = offsets[i] + base_sh;
        offsets[i] = v;
        cursor[i] = v;
    }
    if (b == nb - 1 && t == 0) offsets[n] = tot_sh;
}

__global__ void scatter_kernel(const int* __restrict__ src, const int* __restrict__ dst,
                               int* __restrict__ cursor, int* __restrict__ esrc, int E) {
    int e = blockIdx.x * blockDim.x + threadIdx.x;
    if (e < E) {
        int p = atomicAdd(&cursor[dst[e]], 1);
        esrc[p] = src[e];
    }
}

// ---------------------------------------------------------------------------
// bf16 MFMA GEMM — 64(M) x 128(N) tile, BK=32, plain 2-D grid,
// REGISTER-PREFETCH pipeline: iter k+1's global loads issue right after
// iter k's LDS reads (before the MFMAs), so the ~600-cyc global latency
// overlaps MFMA+barrier instead of serializing (the one knob R4-R14 never
// moved; cp.async-style overlap at source level).
// ---------------------------------------------------------------------------
#define LDT 40

__global__ __launch_bounds__(256) void gemm_kernel(
    const ushort_t* __restrict__ A,    // [M][K] bf16
    const ushort_t* __restrict__ Bt,   // [512][K] bf16 (transposed, padded)
    ushort_t* __restrict__ Cb,         // [M][512] bf16
    int M, int K)
{
    __shared__ __align__(16) ushort_t As[64 * LDT];
    __shared__ __align__(16) ushort_t Bs[128 * LDT];

    int m0 = blockIdx.y * 64;
    int n0 = blockIdx.x * 128;

    int tid  = threadIdx.x;
    int lane = tid & 63;
    int w    = tid >> 6;
    int wm   = (w & 1) * 32;       // wave m-offset
    int wn   = (w >> 1) * 64;      // wave n-offset
    int quad = lane >> 4;
    int c16  = lane & 15;

    f32x4 acc[2][4];
#pragma unroll
    for (int i = 0; i < 2; ++i)
#pragma unroll
        for (int j = 0; j < 4; ++j)
#pragma unroll
            for (int r = 0; r < 4; ++r) acc[i][j][r] = 0.0f;

    // staging coords
    int sr = tid >> 2;              // A row 0..63
    int sk = (tid & 3) * 8;         // A k-chunk
    int gm = m0 + sr;  if (gm > M - 1) gm = M - 1;
    const ushort_t* aptr = A + (size_t)gm * K + sk;
    int br0 = tid >> 2;             // B rows (2 chunks/thread)
    int bk0 = (tid & 3) * 8;
    int br1 = (256 + tid) >> 2;
    int bk1 = bk0;
    const ushort_t* bptr0 = Bt + (size_t)(n0 + br0) * K + bk0;
    const ushort_t* bptr1 = Bt + (size_t)(n0 + br1) * K + bk1;

    uint4 av  = *(const uint4*)(aptr);
    uint4 bv0 = *(const uint4*)(bptr0);
    uint4 bv1 = *(const uint4*)(bptr1);

    for (int k0 = 0; k0 < K; k0 += 32) {
        *(uint4*)&As[sr * LDT + sk]   = av;
        *(uint4*)&Bs[br0 * LDT + bk0] = bv0;
        *(uint4*)&Bs[br1 * LDT + bk1] = bv1;
        __syncthreads();

        short8x af0 = *(const short8x*)&As[(wm +      c16) * LDT + quad * 8];
        short8x af1 = *(const short8x*)&As[(wm + 16 + c16) * LDT + quad * 8];
        short8x bf[4];
#pragma unroll
        for (int nt = 0; nt < 4; ++nt)
            bf[nt] = *(const short8x*)&Bs[(wn + nt * 16 + c16) * LDT + quad * 8];

        // prefetch next iteration's tiles (in flight across MFMAs + barrier)
        if (k0 + 32 < K) {
            av  = *(const uint4*)(aptr  + k0 + 32);
            bv0 = *(const uint4*)(bptr0 + k0 + 32);
            bv1 = *(const uint4*)(bptr1 + k0 + 32);
        }

#pragma unroll
        for (int nt = 0; nt < 4; ++nt) {
            acc[0][nt] = __builtin_amdgcn_mfma_f32_16x16x32_bf16(af0, bf[nt], acc[0][nt], 0, 0, 0);
            acc[1][nt] = __builtin_amdgcn_mfma_f32_16x16x32_bf16(af1, bf[nt], acc[1][nt], 0, 0, 0);
        }
        __syncthreads();
    }

#pragma unroll
    for (int mt = 0; mt < 2; ++mt) {
#pragma unroll
        for (int r = 0; r < 4; ++r) {
            int row = m0 + wm + mt * 16 + quad * 4 + r;
            if (row < M) {
#pragma unroll
                for (int nt = 0; nt < 4; ++nt) {
                    int col = n0 + wn + nt * 16 + c16;
                    Cb[(size_t)row * 512 + col] = f2bf(acc[mt][nt][r]);
                }
            }
        }
    }
}

// ---------------------------------------------------------------------------
// logits: one wave per node (4 nodes/block). Lane l owns channels [8l, 8l+8).
// ---------------------------------------------------------------------------
template<int H>
__global__ __launch_bounds__(256) void logits_kernel(
    const uint4* __restrict__ xpb4,    // [node][64]
    const float* __restrict__ aS, const float* __restrict__ aD,
    float* __restrict__ s_log, float* __restrict__ d_log, int OUTC)
{
    int node = blockIdx.x * 4 + (threadIdx.x >> 6);
    if (node >= NNODES) return;
    int lane = threadIdx.x & 63;
    uint4 p = xpb4[(size_t)node * 64 + lane];
    float xv[8] = {bf_lo(p.x), bf_hi(p.x), bf_lo(p.y), bf_hi(p.y),
                   bf_lo(p.z), bf_hi(p.z), bf_lo(p.w), bf_hi(p.w)};
    int cbase = lane * 8;
    float sv = 0.f, dv = 0.f;
    if (cbase + 7 < OUTC) {
        float4 a0 = ((const float4*)aS)[lane * 2];
        float4 a1 = ((const float4*)aS)[lane * 2 + 1];
        float4 b0 = ((const float4*)aD)[lane * 2];
        float4 b1 = ((const float4*)aD)[lane * 2 + 1];
        sv = xv[0]*a0.x + xv[1]*a0.y + xv[2]*a0.z + xv[3]*a0.w
           + xv[4]*a1.x + xv[5]*a1.y + xv[6]*a1.z + xv[7]*a1.w;
        dv = xv[0]*b0.x + xv[1]*b0.y + xv[2]*b0.z + xv[3]*b0.w
           + xv[4]*b1.x + xv[5]*b1.y + xv[6]*b1.z + xv[7]*b1.w;
    } else {
#pragma unroll
        for (int k = 0; k < 8; ++k) {
            int c = cbase + k;
            if (c < OUTC) { sv += xv[k] * aS[c]; dv += xv[k] * aD[c]; }
        }
    }
    int grp = (H == 4) ? 16 : 64;
    for (int off = 1; off < grp; off <<= 1) {
        sv += __shfl_xor(sv, off);
        dv += __shfl_xor(dv, off);
    }
    if ((lane & (grp - 1)) == 0) {
        int h = (H == 4) ? (lane >> 4) : 0;
        s_log[node * H + h] = sv;
        d_log[node * H + h] = dv;
    }
}

// ---------------------------------------------------------------------------
// edge softmax (wave-per-node, 4 nodes/block): writes ew + wself + zinv.
// ---------------------------------------------------------------------------
template<int H>
__global__ __launch_bounds__(256) void edge_softmax_kernel(
    const float* __restrict__ s, const float* __restrict__ dlog,
    const int* __restrict__ offsets, const int* __restrict__ esrc,
    float* __restrict__ ew, float* __restrict__ wself, float* __restrict__ zinv)
{
    int node = blockIdx.x * 4 + (threadIdx.x >> 6);
    if (node >= NNODES) return;
    int lane = threadIdx.x & 63;
    int e0 = offsets[node], e1 = offsets[node + 1];

    float dh[H], selfe[H], mh[H], zh[H];
#pragma unroll
    for (int h = 0; h < H; ++h) {
        dh[h] = dlog[node * H + h];
        selfe[h] = lrelu(s[node * H + h] + dh[h]);
        mh[h] = selfe[h];
        zh[h] = 0.f;
    }
    for (int j = e0 + lane; j < e1; j += 64) {
        int src = esrc[j];
        if (H == 4) {
            float4 sv = ((const float4*)s)[src];
            mh[0] = fmaxf(mh[0], lrelu(sv.x + dh[0]));
            mh[1] = fmaxf(mh[1], lrelu(sv.y + dh[1]));
            mh[2] = fmaxf(mh[2], lrelu(sv.z + dh[2]));
            mh[3] = fmaxf(mh[3], lrelu(sv.w + dh[3]));
        } else {
            mh[0] = fmaxf(mh[0], lrelu(s[src] + dh[0]));
        }
    }
#pragma unroll
    for (int h = 0; h < H; ++h)
        for (int off = 32; off > 0; off >>= 1)
            mh[h] = fmaxf(mh[h], __shfl_xor(mh[h], off));

    for (int j = e0 + lane; j < e1; j += 64) {
        int src = esrc[j];
        if (H == 4) {
            float4 sv = ((const float4*)s)[src];
            float w0 = __expf(lrelu(sv.x + dh[0]) - mh[0]);
            float w1 = __expf(lrelu(sv.y + dh[1]) - mh[1]);
            float w2 = __expf(lrelu(sv.z + dh[2]) - mh[2]);
            float w3 = __expf(lrelu(sv.w + dh[3]) - mh[3]);
            ((float4*)ew)[j] = make_float4(w0, w1, w2, w3);
            zh[0] += w0; zh[1] += w1; zh[2] += w2; zh[3] += w3;
        } else {
            float w0 = __expf(lrelu(s[src] + dh[0]) - mh[0]);
            ew[j] = w0;
            zh[0] += w0;
        }
    }
#pragma unroll
    for (int h = 0; h < H; ++h)
        for (int off = 32; off > 0; off >>= 1)
            zh[h] += __shfl_xor(zh[h], off);

    if (lane == 0) {
#pragma unroll
        for (int h = 0; h < H; ++h) {
            float ws = __expf(selfe[h] - mh[h]);
            wself[node * H + h] = ws;
            zinv[node * H + h] = 1.0f / (zh[h] + ws);
        }
    }
}

// ---------------------------------------------------------------------------
// SLICED gather (R13, proven): slice pinned per XCD pair, 2.56 MB L2-resident.
// ---------------------------------------------------------------------------
__device__ __forceinline__ void acc8(float* acc, uint4 q, float w) {
    acc[0] += w * bf_lo(q.x); acc[1] += w * bf_hi(q.x);
    acc[2] += w * bf_lo(q.y); acc[3] += w * bf_hi(q.y);
    acc[4] += w * bf_lo(q.z); acc[5] += w * bf_hi(q.z);
    acc[6] += w * bf_lo(q.w); acc[7] += w * bf_hi(q.w);
}

template<int H>
__global__ __launch_bounds__(256) void gather_sliced_kernel(
    const uint4* __restrict__ xpb4,     // [node][64]
    const int* __restrict__ offsets, const int* __restrict__ esrc,
    const float* __restrict__ ew,       // [E][H]
    const float* __restrict__ wself,    // [node][H]
    const float* __restrict__ zinv,     // [node][H]
    const float* __restrict__ bias,     // [OUTC]
    float* __restrict__ out,            // [node][ldo]
    int OUTC, int ldo)
{
    int id = blockIdx.x;
    int xcd = id & 7;
    int slice = xcd >> 1;                       // 0..3 — pinned per XCD pair
    int sub2 = xcd & 1;
    int wv = threadIdx.x >> 6;
    int node = (id >> 3) * 8 + sub2 * 4 + wv;
    if (node >= NNODES) return;
    int lane = threadIdx.x & 63;
    int esub = lane >> 4;                       // edge subgroup 0..3
    int l16 = lane & 15;
    int h = (H == 4) ? slice : 0;
    int rowoff = slice * 16 + l16;              // uint4 index within 64-wide row

    float acc[8];
    if (esub == 0) {
        float ws = wself[node * H + h];
        uint4 p = xpb4[(size_t)node * 64 + rowoff];
        acc[0] = ws * bf_lo(p.x); acc[1] = ws * bf_hi(p.x);
        acc[2] = ws * bf_lo(p.y); acc[3] = ws * bf_hi(p.y);
        acc[4] = ws * bf_lo(p.z); acc[5] = ws * bf_hi(p.z);
        acc[6] = ws * bf_lo(p.w); acc[7] = ws * bf_hi(p.w);
    } else {
#pragma unroll
        for (int k = 0; k < 8; ++k) acc[k] = 0.f;
    }

    int e0 = offsets[node], e1 = offsets[node + 1];
    int j = e0 + esub;
    for (; j + 12 < e1; j += 16) {
        int s0 = esrc[j], s1 = esrc[j + 4], s2 = esrc[j + 8], s3 = esrc[j + 12];
        float w0 = ew[(size_t)j * H + h];
        float w1 = ew[(size_t)(j + 4) * H + h];
        float w2 = ew[(size_t)(j + 8) * H + h];
        float w3 = ew[(size_t)(j + 12) * H + h];
        uint4 q0 = xpb4[(size_t)s0 * 64 + rowoff];
        uint4 q1 = xpb4[(size_t)s1 * 64 + rowoff];
        uint4 q2 = xpb4[(size_t)s2 * 64 + rowoff];
        uint4 q3 = xpb4[(size_t)s3 * 64 + rowoff];
        acc8(acc, q0, w0);
        acc8(acc, q1, w1);
        acc8(acc, q2, w2);
        acc8(acc, q3, w3);
    }
    for (; j < e1; j += 4) {
        int s0 = esrc[j];
        float w0 = ew[(size_t)j * H + h];
        uint4 q0 = xpb4[(size_t)s0 * 64 + rowoff];
        acc8(acc, q0, w0);
    }

    // combine the 4 edge subgroups
#pragma unroll
    for (int k = 0; k < 8; ++k) {
        acc[k] += __shfl_xor(acc[k], 16);
        acc[k] += __shfl_xor(acc[k], 32);
    }

    if (esub == 0) {
        float zi = zinv[node * H + h];
        int cbase = slice * 128 + l16 * 8;
        size_t ob = (size_t)node * ldo + cbase;
        if (cbase + 7 < OUTC) {
            float4 o0 = make_float4(acc[0] * zi + bias[cbase + 0], acc[1] * zi + bias[cbase + 1],
                                    acc[2] * zi + bias[cbase + 2], acc[3] * zi + bias[cbase + 3]);
            float4 o1 = make_float4(acc[4] * zi + bias[cbase + 4], acc[5] * zi + bias[cbase + 5],
                                    acc[6] * zi + bias[cbase + 6], acc[7] * zi + bias[cbase + 7]);
            *(float4*)(out + ob) = o0;
            *(float4*)(out + ob + 4) = o1;
        } else {
#pragma unroll
            for (int k = 0; k < 8; ++k) {
                int c = cbase + k;
                if (c < OUTC) out[ob + k] = acc[k] * zi + bias[c];
            }
        }
    }
}

// ---------------------------------------------------------------------------
// BatchNorm: stats (64-block partials) -> tiny finalize -> wide apply+pack.
// ---------------------------------------------------------------------------
__global__ __launch_bounds__(512) void bn_stats_kernel(const float* __restrict__ h,
                                                       float* __restrict__ psum,
                                                       float* __restrict__ psumsq) {
    int c = threadIdx.x;  // 512
    int b = blockIdx.x;   // 64
    float sm = 0.f, sq = 0.f;
    for (int r = b; r < NNODES; r += 64) {
        float v = h[(size_t)r * 512 + c];
        sm += v;
        sq += v * v;
    }
    psum[b * 512 + c] = sm;
    psumsq[b * 512 + c] = sq;
}

__global__ __launch_bounds__(512) void bn_finalize_kernel(const float* __restrict__ psum,
                                                          const float* __restrict__ psumsq,
                                                          const float* __restrict__ gamma,
                                                          const float* __restrict__ beta,
                                                          float* __restrict__ scale,
                                                          float* __restrict__ shift) {
    int c = threadIdx.x;
    float sm = 0.f, sq = 0.f;
    for (int b = 0; b < 64; ++b) {
        sm += psum[b * 512 + c];
        sq += psumsq[b * 512 + c];
    }
    const float invN = 1.0f / (float)NNODES;
    float mu = sm * invN;
    float var = sq * invN - mu * mu;
    float sc = gamma[c] * rsqrtf(var + BN_EPS);
    scale[c] = sc;
    shift[c] = beta[c] - mu * sc;
}

__global__ __launch_bounds__(256) void bn_apply_kernel(const float* __restrict__ h,
                                                       const float* __restrict__ scale,
                                                       const float* __restrict__ shift,
                                                       uint_t* __restrict__ hbf) {
    int t = threadIdx.x, b = blockIdx.x;   // grid = 256
    int c0 = t * 2, c1 = c0 + 1;
    float sc0 = scale[c0], sc1 = scale[c1];
    float sh0 = shift[c0], sh1 = shift[c1];
    for (int r = b; r < NNODES; r += 256) {
        float2 hv = ((const float2*)(h + (size_t)r * 512))[t];
        float v0 = hv.x * sc0 + sh0;
        float v1 = hv.y * sc1 + sh1;
        v0 = (v0 > 0.f) ? v0 : (__expf(v0) - 1.0f);
        v1 = (v1 > 0.f) ? v1 : (__expf(v1) - 1.0f);
        hbf[r * 256 + t] = ((uint_t)f2bf(v1) << 16) | (uint_t)f2bf(v0);
    }
}

// ---------------------------------------------------------------------------
// launch — 24 dispatches
// ---------------------------------------------------------------------------
extern "C" void kernel_launch(void* const* d_in, const int* in_sizes, int n_in,
                              void* d_out, int out_size, void* d_ws, size_t ws_size,
                              hipStream_t stream) {
    const float* x      = (const float*)d_in[0];
    const int*   ei     = (const int*)d_in[1];
    const float* W1     = (const float*)d_in[2];
    const float* a_src1 = (const float*)d_in[3];
    const float* a_dst1 = (const float*)d_in[4];
    const float* b1     = (const float*)d_in[5];
    const float* g1     = (const float*)d_in[6];
    const float* be1    = (const float*)d_in[7];
    const float* W2     = (const float*)d_in[8];
    const float* a_src2 = (const float*)d_in[9];
    const float* a_dst2 = (const float*)d_in[10];
    const float* b2     = (const float*)d_in[11];
    const float* g2     = (const float*)d_in[12];
    const float* be2    = (const float*)d_in[13];
    const float* W3     = (const float*)d_in[14];
    const float* a_src3 = (const float*)d_in[15];
    const float* a_dst3 = (const float*)d_in[16];
    const float* b3     = (const float*)d_in[17];
    float* out = (float*)d_out;

    const int* e_src = ei;           // edge_index[0]
    const int* e_dst = ei + NEDGES;  // edge_index[1]

    // ---- workspace layout ----
    char* w = (char*)d_ws;
    ushort_t* x_bf = (ushort_t*)w;
    float*    hbuf = (float*)w;                               // alias after L1 GEMM
    float*    ew   = (float*)(w + (size_t)NNODES * HC_ * sizeof(float));  // tail 5.12 MB
    w += (size_t)NNODES * INF_ * sizeof(ushort_t);            // 25.6 MB
    uint_t* xpb = (uint_t*)w;  w += (size_t)NNODES * HC_ * sizeof(ushort_t);
    uint_t* hbf = (uint_t*)w;  w += (size_t)NNODES * HC_ * sizeof(ushort_t);
    ushort_t* Wt1 = (ushort_t*)w; w += (size_t)HC_ * INF_ * sizeof(ushort_t);
    ushort_t* Wt2 = (ushort_t*)w; w += (size_t)HC_ * HC_ * sizeof(ushort_t);
    ushort_t* Wt3 = (ushort_t*)w; w += (size_t)HC_ * HC_ * sizeof(ushort_t);
    int* counts  = (int*)w;    w += NNODES * sizeof(int);
    float* s_log = (float*)w;  w += NNODES * HEADS_ * sizeof(float);
    float* d_log = (float*)w;  w += NNODES * HEADS_ * sizeof(float);
    float* wself = (float*)w;  w += NNODES * HEADS_ * sizeof(float);
    float* zinv  = (float*)w;  w += NNODES * HEADS_ * sizeof(float);
    float* bnscale = (float*)w; w += HC_ * sizeof(float);
    float* bnshift = (float*)w; w += HC_ * sizeof(float);
    float* psum  = (float*)w;  w += 64 * HC_ * sizeof(float);
    float* psumsq= (float*)w;  w += 64 * HC_ * sizeof(float);
    int* offsets = (int*)w;    w += (NNODES + 1) * sizeof(int);
    int* cursor  = (int*)w;    w += NNODES * sizeof(int);
    int* esrc    = (int*)w;    w += NEDGES * sizeof(int);
    int* bsum    = (int*)w;    w += 64 * sizeof(int);

    dim3 gg(HC_ / 128, (NNODES + 63) / 64);          // (4, 157) — 64x128 tile
    const int lgGrid = (NNODES + 3) / 4;             // 2500 (logits / softmax)
    const int gaGrid = ((NNODES + 7) / 8) * 8;       // 10000 (sliced gather)
    const int scanBlocks = (NNODES + 255) / 256;     // 40

    zero_kernel<<<32, 256, 0, stream>>>((float*)counts, NNODES);
    count_kernel<<<(NEDGES + 255) / 256, 256, 0, stream>>>(e_dst, counts, NEDGES);
    scan1_kernel<<<scanBlocks, 256, 0, stream>>>(counts, offsets, bsum, NNODES);
    scan3b_kernel<<<scanBlocks, 256, 0, stream>>>(offsets, cursor, bsum, scanBlocks, NNODES);
    scatter_kernel<<<(NEDGES + 255) / 256, 256, 0, stream>>>(e_src, e_dst, cursor, esrc, NEDGES);
    {
        int TOT = CVX + CN1 + CN2 + CN3;
        convall_kernel<<<(TOT + 255) / 256, 256, 0, stream>>>(x, W1, W2, W3, x_bf, Wt1, Wt2, Wt3);
    }

    // ---- Layer 1 ----
    gemm_kernel<<<gg, 256, 0, stream>>>(x_bf, Wt1, (ushort_t*)xpb, NNODES, INF_);
    logits_kernel<HEADS_><<<lgGrid, 256, 0, stream>>>((const uint4*)xpb, a_src1, a_dst1, s_log, d_log, HC_);
    edge_softmax_kernel<HEADS_><<<lgGrid, 256, 0, stream>>>(s_log, d_log, offsets, esrc, ew, wself, zinv);
    gather_sliced_kernel<HEADS_><<<gaGrid, 256, 0, stream>>>((const uint4*)xpb, offsets, esrc,
        ew, wself, zinv, b1, hbuf, HC_, HC_);
    bn_stats_kernel<<<64, 512, 0, stream>>>(hbuf, psum, psumsq);
    bn_finalize_kernel<<<1, 512, 0, stream>>>(psum, psumsq, g1, be1, bnscale, bnshift);
    bn_apply_kernel<<<256, 256, 0, stream>>>(hbuf, bnscale, bnshift, hbf);

    // ---- Layer 2 ----
    gemm_kernel<<<gg, 256, 0, stream>>>((const ushort_t*)hbf, Wt2, (ushort_t*)xpb, NNODES, HC_);
    logits_kernel<HEADS_><<<lgGrid, 256, 0, stream>>>((const uint4*)xpb, a_src2, a_dst2, s_log, d_log, HC_);
    edge_softmax_kernel<HEADS_><<<lgGrid, 256, 0, stream>>>(s_log, d_log, offsets, esrc, ew, wself, zinv);
    gather_sliced_kernel<HEADS_><<<gaGrid, 256, 0, stream>>>((const uint4*)xpb, offsets, esrc,
        ew, wself, zinv, b2, hbuf, HC_, HC_);
    bn_stats_kernel<<<64, 512, 0, stream>>>(hbuf, psum, psumsq);
    bn_finalize_kernel<<<1, 512, 0, stream>>>(psum, psumsq, g2, be2, bnscale, bnshift);
    bn_apply_kernel<<<256, 256, 0, stream>>>(hbuf, bnscale, bnshift, hbf);

    // ---- Layer 3 (H=1, N=500) ----
    gemm_kernel<<<gg, 256, 0, stream>>>((const ushort_t*)hbf, Wt3, (ushort_t*)xpb, NNODES, HC_);
    logits_kernel<1><<<lgGrid, 256, 0, stream>>>((const uint4*)xpb, a_src3, a_dst3, s_log, d_log, OUTF_);
    edge_softmax_kernel<1><<<lgGrid, 256, 0, stream>>>(s_log, d_log, offsets, esrc, ew, wself, zinv);
    gather_sliced_kernel<1><<<gaGrid, 256, 0, stream>>>((const uint4*)xpb, offsets, esrc,
        ew, wself, zinv, b3, out, OUTF_, OUTF_);
}